// Round 6
// baseline (2002.808 us; speedup 1.0000x reference)
//
#include <hip/hip_runtime.h>
#include <cstdint>
#include <cstddef>

#define SEQ   128
#define BB    32
#define EE    1024
#define HH    1024
#define G4    4096
#define VV    32000
#define NROWS 4096   // SEQ*BB

typedef _Float16 h16x8 __attribute__((ext_vector_type(8)));
typedef _Float16 h16x4 __attribute__((ext_vector_type(4)));
typedef float f32x4  __attribute__((ext_vector_type(4)));
typedef unsigned u32x4 __attribute__((ext_vector_type(4)));

#define AS_G(p) ((const __attribute__((address_space(1))) void*)(p))
#define AS_L(p) ((__attribute__((address_space(3))) void*)(p))

__device__ __forceinline__ float sigmf(float x) { return 1.0f / (1.0f + expf(-x)); }

// ---------------- ws layout (bytes) ----------------
// sync region: 64 dwords pad @0, dense arrive[256] dwords @256 (16 cache lines)
#define OFF_SYNC    0ull
#define OFF_HFRAG   33024ull                  // 6 slots * 32768 f16 = 393216 B
#define OFF_EMB     426240ull                 // [4096][1024] f16
#define OFF_X0      8814848ull                // [4096][4096] f16
#define OFF_WIH0    42369280ull               // [4096][1024] f16
#define OFF_WP4     50757888ull               // 256 wg * 65536 f16
#define OFF_WP0     84312320ull               // 256 wg * 16384 f16
#define OFF_EMBW    92700928ull               // [32000][1024] f16
#define OFF_WIN     158236928ull              // [1024][1024] f16
#define OFF_WOUT    160334080ull              // [1024][2048] f16
#define OFF_ENC     164528384ull              // [64][32][1024] f16
#define OFF_H2ALL   168722688ull              // [4096][1024] f16
#define OFF_CONCAT  177111296ull              // [4096][2048] f16
#define OFF_TARGET  193888512ull              // [4096][1024] f16
#define OFF_HT      202277120ull              // [4096][1024] f16
#define WS_NEEDED   210665728ull

// ---------------- f32 -> f16 convert (vectorized, grid-stride) ----------------
__global__ __launch_bounds__(256) void k_conv(const float* __restrict__ s,
                                              _Float16* __restrict__ d, int n4) {
  int i = blockIdx.x * blockDim.x + threadIdx.x;
  int st = gridDim.x * blockDim.x;
  for (; i < n4; i += st) {
    float4 v = ((const float4*)s)[i];
    h16x4 o; o[0] = (_Float16)v.x; o[1] = (_Float16)v.y; o[2] = (_Float16)v.z; o[3] = (_Float16)v.w;
    ((h16x4*)d)[i] = o;
  }
}

// ---------------- embedding gather -> f16 ----------------
__global__ __launch_bounds__(256) void k_gather(const int* __restrict__ tok,
                                                const float* __restrict__ embW,
                                                _Float16* __restrict__ emb) {
  int row = blockIdx.x;                 // row = t*32+b
  int t = tok[row];
  float4 v = ((const float4*)(embW + (size_t)t * EE))[threadIdx.x];
  h16x4 o; o[0] = (_Float16)v.x; o[1] = (_Float16)v.y; o[2] = (_Float16)v.z; o[3] = (_Float16)v.w;
  ((h16x4*)(emb + (size_t)row * EE))[threadIdx.x] = o;
}

// ---------------- pack 4 LDS-resident matrices (Wih1,Whh1,Wih2,Whh2) ----------------
// Wpack4[w][mat][jj][k_lds] = W[layer][row(w,jj)][k_lds ^ ((jj&7)<<3)]  (XOR pre-swizzle)
__global__ __launch_bounds__(256) void k_packw4(const float* __restrict__ Wih,
                                                const float* __restrict__ Whh,
                                                _Float16* __restrict__ out) {
  int i = blockIdx.x * blockDim.x + threadIdx.x;
  int st = gridDim.x * blockDim.x;
  const int total = 256 * 65536;
  for (; i < total; i += st) {
    int w = i >> 16, rem = i & 65535;
    int mat = rem >> 14, jj = (rem >> 10) & 15, k = rem & 1023;
    int layer = 1 + (mat >> 1), isHH = mat & 1;
    int row = ((jj >> 2) << 10) + (w << 2) + (jj & 3);
    int ks = k ^ ((jj & 7) << 3);
    const float* src = (isHH ? Whh : Wih) + (size_t)layer * G4 * 1024 + (size_t)row * 1024 + ks;
    out[i] = (_Float16)(*src);
  }
}

// ---------------- pack Whh0 fragment-linear: [w][ks 0..31][lane 0..63][e 0..7] ----------------
__global__ __launch_bounds__(256) void k_packw0(const float* __restrict__ Whh,
                                                _Float16* __restrict__ out) {
  int i = blockIdx.x * blockDim.x + threadIdx.x;
  int st = gridDim.x * blockDim.x;
  const int total = 256 * 16384;
  for (; i < total; i += st) {
    int w = i >> 14, rem = i & 16383;
    int ks = rem >> 9, lane = (rem >> 3) & 63, e = rem & 7;
    int jj = lane & 15, q = lane >> 4;
    int row = ((jj >> 2) << 10) + (w << 2) + (jj & 3);
    int k = ks * 32 + q * 8 + e;
    out[i] = (_Float16)Whh[(size_t)row * 1024 + k];   // layer 0
  }
}

// ---------------- init: sync flags + initial h fragments ----------------
// parity init per layer: l0 -> slot[0][1], l1 -> slot[1][0], l2 -> slot[2][1]
__global__ __launch_bounds__(256) void k_init(const float* __restrict__ h0,
                                              _Float16* __restrict__ hfrag,
                                              unsigned* __restrict__ sync) {
  int i = blockIdx.x * blockDim.x + threadIdx.x;
  if (i < 64 + 256) sync[i] = 0u;   // pad + dense arrive flags
  if (i >= 3 * BB * HH) return;
  int l = i >> 15, rem = i & 32767;
  int b = rem >> 10, n = rem & 1023;
  int parI = (l == 1) ? 0 : 1;
  int tbb = b >> 4, ks = n >> 5, q = (n >> 3) & 3, e = n & 7;
  int lane2 = (b & 15) | (q << 4);
  hfrag[(size_t)(l * 2 + parI) * 32768 + ((size_t)(tbb * 32 + ks) * 64 + lane2) * 8 + e] =
      (_Float16)h0[i];
}

// ---------------- generic 128x128 BT GEMM (A[M,K] f16, B[N,K] f16) ----------------
// staging via global_load_lds width=16; XCD-aware block swizzle (grid % 8 == 0)
// EPI: 0 = f32 + bias1 ; 1 = f16 ; 2 = f16(tanh) ; 3 = f16 + bias1 + bias2
template <int EPI>
__global__ __launch_bounds__(256) void k_gemm(const _Float16* __restrict__ A,
                                              const _Float16* __restrict__ B,
                                              void* __restrict__ C, int M, int N, int K,
                                              const float* __restrict__ bias1,
                                              const float* __restrict__ bias2) {
  __shared__ _Float16 As[2][128 * 32];
  __shared__ _Float16 Bs[2][128 * 32];
  const int ntn = N / 128;
  // bijective XCD swizzle: consecutive blocks within an XCD share the A panel
  const int nwg = gridDim.x;
  const int bid = (blockIdx.x & 7) * (nwg >> 3) + (blockIdx.x >> 3);
  const int tm = bid / ntn, tn = bid % ntn;
  const int tid = threadIdx.x, lane = tid & 63;
  const int wv = tid >> 6, wr = wv >> 1, wc = wv & 1;
  f32x4 acc[4][4] = {};

  auto stage = [&](int buf, int k0) {
#pragma unroll
    for (int i = 0; i < 2; ++i) {
      int eo = (i * 256 + tid) * 8;
      int r = eo >> 5, c = eo & 31;
      __builtin_amdgcn_global_load_lds(AS_G(A + (size_t)(tm * 128 + r) * K + k0 + c),
                                       AS_L(&As[buf][eo]), 16, 0, 0);
      __builtin_amdgcn_global_load_lds(AS_G(B + (size_t)(tn * 128 + r) * K + k0 + c),
                                       AS_L(&Bs[buf][eo]), 16, 0, 0);
    }
  };
  stage(0, 0);
  __syncthreads();
  const int nk = K / 32;
  for (int kt = 0; kt < nk; ++kt) {
    if (kt + 1 < nk) stage((kt + 1) & 1, (kt + 1) * 32);
    const int buf = kt & 1;
    h16x8 af[4], bfr[4];
#pragma unroll
    for (int mi = 0; mi < 4; ++mi)
      af[mi] = *(const h16x8*)&As[buf][(wr * 64 + mi * 16 + (lane & 15)) * 32 + (lane >> 4) * 8];
#pragma unroll
    for (int ni = 0; ni < 4; ++ni)
      bfr[ni] = *(const h16x8*)&Bs[buf][(wc * 64 + ni * 16 + (lane & 15)) * 32 + (lane >> 4) * 8];
#pragma unroll
    for (int mi = 0; mi < 4; ++mi)
#pragma unroll
      for (int ni = 0; ni < 4; ++ni)
        acc[mi][ni] = __builtin_amdgcn_mfma_f32_16x16x32_f16(af[mi], bfr[ni], acc[mi][ni], 0, 0, 0);
    __syncthreads();
  }
  const int rbase = tm * 128 + wr * 64;
  const int cbase = tn * 128 + wc * 64;
#pragma unroll
  for (int mi = 0; mi < 4; ++mi) {
#pragma unroll
    for (int ni = 0; ni < 4; ++ni) {
#pragma unroll
      for (int r = 0; r < 4; ++r) {
        int mm = rbase + mi * 16 + (lane >> 4) * 4 + r;
        int nn = cbase + ni * 16 + (lane & 15);
        float v = acc[mi][ni][r];
        if (EPI == 0) {
          ((float*)C)[(size_t)mm * N + nn] = v + bias1[nn];
        } else if (EPI == 1) {
          ((_Float16*)C)[(size_t)mm * N + nn] = (_Float16)v;
        } else if (EPI == 2) {
          ((_Float16*)C)[(size_t)mm * N + nn] = (_Float16)tanhf(v);
        } else {
          ((_Float16*)C)[(size_t)mm * N + nn] = (_Float16)(v + bias1[nn] + bias2[nn]);
        }
      }
    }
  }
}

// ---------------- persistent pipelined LSTM recurrence ----------------
// 256 wgs x 512 thr. wg w owns hidden units n = 4w..4w+3 (16 gate rows).
// Tick tau: l0 computes h0(tau), l1 computes h1(tau-1), l2 computes h2(tau-2).
// Fence-free exchange: h via agent-scope (sc1) 8B stores; dense 4B flag per wg
// (16 cache lines total); every wg polls all 256 flags with ONE dwordx4 sc1
// load per lane; acquire fence (inv) then cached h reads (L2-amortized/XCD).
// Regular launch; co-residency structural: 152KB LDS => 1 wg/CU, grid 256 == CU count.
__global__ __launch_bounds__(512) void k_recur(const _Float16* __restrict__ Wp4,
                                               const _Float16* __restrict__ Wp0,
                                               const _Float16* __restrict__ X0bf,
                                               _Float16* __restrict__ hfrag,
                                               _Float16* __restrict__ h2all,
                                               _Float16* __restrict__ concat,
                                               const float* __restrict__ bih,
                                               const float* __restrict__ bhh,
                                               const float* __restrict__ c0p,
                                               unsigned* __restrict__ sync) {
  extern __shared__ char lds[];
  _Float16* ldsW = (_Float16*)lds;                 // 65536 f16
  float* redbuf = (float*)(lds + 131072);          // [3][3][2][256]
  _Float16* hstage = (_Float16*)(lds + 131072);    // [3][128] (reused after redbuf)
  float* gbuf = (float*)(lds + 149504);            // [3][32][16]
  unsigned* arrive = sync + 64;                    // dense: arrive[w], 4B each

  const int w = blockIdx.x;
  const int tid = threadIdx.x, lane = tid & 63, wv = tid >> 6;
  const int tb = wv & 1, kq = wv >> 1;
  const int row = (lane >> 4) * 4, col = lane & 15;

  // preload LDS weights (linear copy; swizzle pre-applied by k_packw4)
  for (int i = 0; i < 16; ++i) {
    int eo = (i * 512 + tid) * 8;
    *(h16x8*)&ldsW[eo] = *(const h16x8*)(Wp4 + (size_t)w * 65536 + eo);
  }
  // Whh0 fragments in registers
  h16x8 w0reg[8];
#pragma unroll
  for (int i = 0; i < 8; ++i)
    w0reg[i] = *(const h16x8*)(Wp0 + (size_t)w * 16384 + ((size_t)(kq * 8 + i) * 64 + lane) * 8);

  // per-thread epilogue state (threads 0..127 own (b, ni))
  const int eb = tid >> 2, eni = tid & 3, en = w * 4 + eni;
  float c0r = 0.f, c1r = 0.f, c2r = 0.f;
  float b1r[4] = {0, 0, 0, 0}, b2r[4] = {0, 0, 0, 0};
  if (tid < 128) {
    c0r = c0p[0 * BB * HH + eb * HH + en];
    c1r = c0p[1 * BB * HH + eb * HH + en];
    c2r = c0p[2 * BB * HH + eb * HH + en];
#pragma unroll
    for (int g = 0; g < 4; ++g) {
      b1r[g] = bih[1 * G4 + g * 1024 + en] + bhh[1 * G4 + g * 1024 + en];
      b2r[g] = bih[2 * G4 + g * 1024 + en] + bhh[2 * G4 + g * 1024 + en];
    }
  }
  // pack-phase constants: h slot offset for 8B run r (=batch row) of this wg
  const int pk_l = tid >> 5, pk_r = tid & 31;
  const size_t pk_idx = ((size_t)(((pk_r >> 4) * 32 + (w >> 3)) * 64 + (pk_r & 15) +
                                  (((w >> 1) & 3) << 4))) * 8 + 4 * (w & 1);
  __syncthreads();

  for (int tau = 0; tau < 130; ++tau) {
    const int p = tau & 1;
    const _Float16* h0r = hfrag + (size_t)(0 + (1 - p)) * 32768;
    const _Float16* h1r = hfrag + (size_t)(2 + (1 - p)) * 32768;
    const _Float16* h2r = hfrag + (size_t)(4 + (1 - p)) * 32768;

    // A fragments (coalesced 16B/lane); inactive-layer reads feed discarded accs
    h16x8 a0[8], a1[8], a2[8];
#pragma unroll
    for (int i = 0; i < 8; ++i) {
      int ks = kq * 8 + i;
      size_t off = ((size_t)(tb * 32 + ks) * 64 + lane) * 8;
      a0[i] = *(const h16x8*)(h0r + off);
      a1[i] = *(const h16x8*)(h1r + off);
      a2[i] = *(const h16x8*)(h2r + off);
    }
    // hoist X0 gate loads: LLC latency hides under fragment loads + MFMA
    float xg0 = 0.f, xg1 = 0.f, xg2 = 0.f, xg3 = 0.f;
    if (tid < 128 && tau < 128) {
      size_t xb = ((size_t)(tau * BB + eb)) * G4 + en;
      xg0 = (float)X0bf[xb];        xg1 = (float)X0bf[xb + 1024];
      xg2 = (float)X0bf[xb + 2048]; xg3 = (float)X0bf[xb + 3072];
    }
    f32x4 acc0 = {}, acc1 = {}, acc2 = {};
#pragma unroll
    for (int i = 0; i < 8; ++i) {
      int ks = kq * 8 + i;
      int jj = lane & 15, q = lane >> 4;
      int kk = (ks * 32 + q * 8) ^ ((jj & 7) << 3);
      const h16x8 bw1i = *(const h16x8*)&ldsW[0 * 16384 + jj * 1024 + kk];
      const h16x8 bw1h = *(const h16x8*)&ldsW[1 * 16384 + jj * 1024 + kk];
      const h16x8 bw2i = *(const h16x8*)&ldsW[2 * 16384 + jj * 1024 + kk];
      const h16x8 bw2h = *(const h16x8*)&ldsW[3 * 16384 + jj * 1024 + kk];
      acc0 = __builtin_amdgcn_mfma_f32_16x16x32_f16(a0[i], w0reg[i], acc0, 0, 0, 0);
      acc1 = __builtin_amdgcn_mfma_f32_16x16x32_f16(a0[i], bw1i, acc1, 0, 0, 0);
      acc1 = __builtin_amdgcn_mfma_f32_16x16x32_f16(a1[i], bw1h, acc1, 0, 0, 0);
      acc2 = __builtin_amdgcn_mfma_f32_16x16x32_f16(a1[i], bw2i, acc2, 0, 0, 0);
      acc2 = __builtin_amdgcn_mfma_f32_16x16x32_f16(a2[i], bw2h, acc2, 0, 0, 0);
    }
    // cross-wave K reduction
    if (kq >= 1) {
      int s = kq - 1;
#pragma unroll
      for (int r = 0; r < 4; ++r) {
        redbuf[((0 * 3 + s) * 2 + tb) * 256 + (row + r) * 16 + col] = acc0[r];
        redbuf[((1 * 3 + s) * 2 + tb) * 256 + (row + r) * 16 + col] = acc1[r];
        redbuf[((2 * 3 + s) * 2 + tb) * 256 + (row + r) * 16 + col] = acc2[r];
      }
    }
    __syncthreads();
    if (kq == 0) {
#pragma unroll
      for (int r = 0; r < 4; ++r) {
        float v0 = acc0[r], v1 = acc1[r], v2 = acc2[r];
#pragma unroll
        for (int s = 0; s < 3; ++s) {
          v0 += redbuf[((0 * 3 + s) * 2 + tb) * 256 + (row + r) * 16 + col];
          v1 += redbuf[((1 * 3 + s) * 2 + tb) * 256 + (row + r) * 16 + col];
          v2 += redbuf[((2 * 3 + s) * 2 + tb) * 256 + (row + r) * 16 + col];
        }
        gbuf[(0 * 32 + tb * 16 + row + r) * 16 + col] = v0;
        gbuf[(1 * 32 + tb * 16 + row + r) * 16 + col] = v1;
        gbuf[(2 * 32 + tb * 16 + row + r) * 16 + col] = v2;
      }
    }
    __syncthreads();
    // elementwise LSTM epilogue -> hstage (LDS) + h2all/concat (regular stores)
    if (tid < 128) {
      if (tau < 128) {  // layer 0: X0 already holds x@Wih0^T + b_ih0 + b_hh0
        float gi = gbuf[(0 * 32 + eb) * 16 + eni] + xg0;
        float gf = gbuf[(0 * 32 + eb) * 16 + 4 + eni] + xg1;
        float gg = gbuf[(0 * 32 + eb) * 16 + 8 + eni] + xg2;
        float go = gbuf[(0 * 32 + eb) * 16 + 12 + eni] + xg3;
        c0r = sigmf(gf) * c0r + sigmf(gi) * tanhf(gg);
        hstage[0 * 128 + tid] = (_Float16)(sigmf(go) * tanhf(c0r));
      }
      if (tau >= 1 && tau < 129) {  // layer 1
        float gi = gbuf[(1 * 32 + eb) * 16 + eni] + b1r[0];
        float gf = gbuf[(1 * 32 + eb) * 16 + 4 + eni] + b1r[1];
        float gg = gbuf[(1 * 32 + eb) * 16 + 8 + eni] + b1r[2];
        float go = gbuf[(1 * 32 + eb) * 16 + 12 + eni] + b1r[3];
        c1r = sigmf(gf) * c1r + sigmf(gi) * tanhf(gg);
        hstage[1 * 128 + tid] = (_Float16)(sigmf(go) * tanhf(c1r));
      }
      if (tau >= 2) {  // layer 2
        float gi = gbuf[(2 * 32 + eb) * 16 + eni] + b2r[0];
        float gf = gbuf[(2 * 32 + eb) * 16 + 4 + eni] + b2r[1];
        float gg = gbuf[(2 * 32 + eb) * 16 + 8 + eni] + b2r[2];
        float go = gbuf[(2 * 32 + eb) * 16 + 12 + eni] + b2r[3];
        c2r = sigmf(gf) * c2r + sigmf(gi) * tanhf(gg);
        float h = sigmf(go) * tanhf(c2r);
        _Float16 hb = (_Float16)h;
        hstage[2 * 128 + tid] = hb;
        int t2 = tau - 2;
        h2all[(size_t)(t2 * BB + eb) * HH + en] = hb;
        concat[(size_t)(t2 * BB + eb) * 2048 + 1024 + en] = hb;
      }
    }
    __syncthreads();   // hstage visible in LDS
    // pack phase: 96 threads emit one 8B agent-scope (sc1) store each — no wbl2
    {
      bool act = (tid < 96) &&
                 ((pk_l == 0) ? (tau < 128)
                  : (pk_l == 1) ? (tau >= 1 && tau < 129) : (tau >= 2));
      if (act) {
        unsigned long long v = *(const unsigned long long*)&hstage[pk_l * 128 + pk_r * 4];
        __hip_atomic_store(
            (unsigned long long*)(hfrag + (size_t)(pk_l * 2 + p) * 32768 + pk_idx), v,
            __ATOMIC_RELAXED, __HIP_MEMORY_SCOPE_AGENT);
      }
      asm volatile("s_waitcnt vmcnt(0)" ::: "memory");   // own sc1 stores at LLC
    }
    __syncthreads();   // all pack stores complete before flag
    if (tid == 0)
      __hip_atomic_store(&arrive[w], (unsigned)(tau + 1), __ATOMIC_RELAXED,
                         __HIP_MEMORY_SCOPE_AGENT);
    if (tau < 129) {   // last tick: no one consumes, skip the wait
      if (tid < 64) {
        const unsigned* ap = arrive + tid * 4;   // lane covers flags 4t..4t+3 (16B)
        const unsigned tgt = (unsigned)(tau + 1);
        for (;;) {
          u32x4 v;
          // load+wait fused in one asm so the compare can't be hoisted (rule #18)
          asm volatile("global_load_dwordx4 %0, %1, off sc0 sc1\n\ts_waitcnt vmcnt(0)"
                       : "=v"(v) : "v"(ap) : "memory");
          bool ok = (v[0] >= tgt) & (v[1] >= tgt) & (v[2] >= tgt) & (v[3] >= tgt);
          if (__all(ok)) break;
        }
        __builtin_amdgcn_fence(__ATOMIC_ACQUIRE, "agent");  // inv L1/L2, no writeback
      }
      __syncthreads();
    }
  }
}

// ---------------- fused scores+softmax+weighted-context per (t,b) ----------------
__global__ __launch_bounds__(256) void k_attn(const _Float16* __restrict__ target,
                                              const _Float16* __restrict__ encb,
                                              _Float16* __restrict__ concat) {
  __shared__ float sc[64];
  __shared__ float att[64];
  int m = blockIdx.x, b = m & 31;
  int tid = threadIdx.x, lane = tid & 63, wv = tid >> 6;
  const h16x8* tp = (const h16x8*)(target + (size_t)m * EE + lane * 16);
  h16x8 tg0 = tp[0], tg1 = tp[1];
  for (int si = 0; si < 16; ++si) {
    int s = wv * 16 + si;
    const h16x8* ep = (const h16x8*)(encb + ((size_t)s * BB + b) * EE + lane * 16);
    h16x8 e0 = ep[0], e1 = ep[1];
    float a = 0.f;
#pragma unroll
    for (int j = 0; j < 8; ++j) a += (float)e0[j] * (float)tg0[j];
#pragma unroll
    for (int j = 0; j < 8; ++j) a += (float)e1[j] * (float)tg1[j];
#pragma unroll
    for (int off = 32; off >= 1; off >>= 1) a += __shfl_xor(a, off);
    if (lane == 0) sc[s] = a;
  }
  __syncthreads();
  if (wv == 0) {
    float v = sc[lane], mx = v;
#pragma unroll
    for (int off = 32; off >= 1; off >>= 1) mx = fmaxf(mx, __shfl_xor(mx, off));
    float e = expf(v - mx), sm = e;
#pragma unroll
    for (int off = 32; off >= 1; off >>= 1) sm += __shfl_xor(sm, off);
    att[lane] = e / sm;
  }
  __syncthreads();
  int e4 = tid * 4;
  float a0 = 0, a1 = 0, a2 = 0, a3 = 0;
  for (int s = 0; s < 64; ++s) {
    float wgt = att[s];
    h16x4 ev = *(const h16x4*)(encb + ((size_t)s * BB + b) * EE + e4);
    a0 += wgt * (float)ev[0]; a1 += wgt * (float)ev[1];
    a2 += wgt * (float)ev[2]; a3 += wgt * (float)ev[3];
  }
  h16x4 o; o[0] = (_Float16)a0; o[1] = (_Float16)a1; o[2] = (_Float16)a2; o[3] = (_Float16)a3;
  *(h16x4*)(concat + (size_t)m * 2048 + e4) = o;
}

// ---------------- host ----------------
extern "C" void kernel_launch(void* const* d_in, const int* in_sizes, int n_in,
                              void* d_out, int out_size, void* d_ws, size_t ws_size,
                              hipStream_t stream) {
  const int* tokens = (const int*)d_in[0];
  const float* embW = (const float*)d_in[1];
  const float* Wih = (const float*)d_in[2];
  const float* Whh = (const float*)d_in[3];
  const float* bih = (const float*)d_in[4];
  const float* bhh = (const float*)d_in[5];
  const float* Win = (const float*)d_in[6];
  const float* Wout = (const float*)d_in[7];
  const float* finalb = (const float*)d_in[8];
  const float* enc = (const float*)d_in[9];
  const float* h0 = (const float*)d_in[10];
  const float* c0 = (const float*)d_in[11];
  (void)in_sizes; (void)n_in; (void)out_size;
  if (ws_size < WS_NEEDED) return;

  char* ws = (char*)d_ws;
  unsigned* sync = (unsigned*)(ws + OFF_SYNC);
  _Float16* hfrag = (_Float16*)(ws + OFF_HFRAG);
  _Float16* emb = (_Float16*)(ws + OFF_EMB);
  _Float16* X0bf = (_Float16*)(ws + OFF_X0);
  _Float16* Wih0b = (_Float16*)(ws + OFF_WIH0);
  _Float16* Wp4 = (_Float16*)(ws + OFF_WP4);
  _Float16* Wp0 = (_Float16*)(ws + OFF_WP0);
  _Float16* embWb = (_Float16*)(ws + OFF_EMBW);
  _Float16* Winb = (_Float16*)(ws + OFF_WIN);
  _Float16* Woutb = (_Float16*)(ws + OFF_WOUT);
  _Float16* encb = (_Float16*)(ws + OFF_ENC);
  _Float16* h2all = (_Float16*)(ws + OFF_H2ALL);
  _Float16* concat = (_Float16*)(ws + OFF_CONCAT);
  _Float16* target = (_Float16*)(ws + OFF_TARGET);
  _Float16* ht = (_Float16*)(ws + OFF_HT);

  const unsigned LDSB = 155648;  // 128KB weights + 18KB redbuf + 6KB gbuf
  static int lds_set = 0;
  if (!lds_set) {
    hipFuncSetAttribute((const void*)k_recur, hipFuncAttributeMaxDynamicSharedMemorySize,
                        (int)LDSB);
    lds_set = 1;   // attribute is sticky on the function; setting once is enough
  }

  // prep: converts / packs / init
  k_conv<<<4096, 256, 0, stream>>>(embW, embWb, VV * EE / 4);
  k_conv<<<1024, 256, 0, stream>>>(Wih, Wih0b, G4 * EE / 4);       // layer-0 W_ih
  k_conv<<<512, 256, 0, stream>>>(Win, Winb, EE * EE / 4);
  k_conv<<<512, 256, 0, stream>>>(Wout, Woutb, EE * 2048 / 4);
  k_conv<<<512, 256, 0, stream>>>(enc, encb, 64 * BB * EE / 4);
  k_gather<<<NROWS, 256, 0, stream>>>(tokens, embW, emb);
  k_packw4<<<8192, 256, 0, stream>>>(Wih, Whh, Wp4);
  k_packw0<<<4096, 256, 0, stream>>>(Whh, Wp0);
  k_init<<<384, 256, 0, stream>>>(h0, hfrag, sync);

  // X0 = emb @ Wih0^T + b_ih0 + b_hh0   -> f16 [4096,4096]
  k_gemm<3><<<32 * 32, 256, 0, stream>>>(emb, Wih0b, X0bf, NROWS, G4, EE, bih, bhh);

  // recurrence: REGULAR launch (graph-capturable); co-residency structural
  k_recur<<<256, 512, LDSB, stream>>>(Wp4, Wp0, X0bf, hfrag, h2all, concat,
                                      bih, bhh, c0, sync);

  // attention chain
  k_gemm<1><<<32 * 8, 256, 0, stream>>>(h2all, Winb, target, NROWS, EE, EE, nullptr, nullptr);
  k_attn<<<NROWS, 256, 0, stream>>>(target, encb, concat);
  k_gemm<2><<<32 * 8, 256, 0, stream>>>(concat, Woutb, ht, NROWS, EE, 2048, nullptr, nullptr);

  // logits = ht @ embW^T + final_b  -> f32 d_out
  k_gemm<0><<<32 * 250, 256, 0, stream>>>(ht, embWb, d_out, NROWS, VV, EE, finalb, nullptr);
}

// Round 7
// 1758.000 us; speedup vs baseline: 1.1393x; 1.1393x over previous
//
#include <hip/hip_runtime.h>
#include <cstdint>
#include <cstddef>

#define SEQ   128
#define BB    32
#define EE    1024
#define HH    1024
#define G4    4096
#define VV    32000
#define NROWS 4096   // SEQ*BB

typedef _Float16 h16x8 __attribute__((ext_vector_type(8)));
typedef _Float16 h16x4 __attribute__((ext_vector_type(4)));
typedef float f32x4  __attribute__((ext_vector_type(4)));

#define AS_G(p) ((const __attribute__((address_space(1))) void*)(p))
#define AS_L(p) ((__attribute__((address_space(3))) void*)(p))

__device__ __forceinline__ float sigmf(float x) { return 1.0f / (1.0f + expf(-x)); }

// ---------------- ws layout (bytes) ----------------
// sync region (40960 B): pad[64] dwords @0; arrive[256] strided 128B @dword 64;
// summary[8] strided 128B @dword 64+8192.
#define OFF_SYNC    0ull
#define OFF_HFRAG   40960ull                  // 6 slots * 32768 f16 = 393216 B
#define OFF_EMB     434176ull                 // [4096][1024] f16
#define OFF_X0      8822784ull                // [4096][4096] f16
#define OFF_WIH0    42377216ull               // [4096][1024] f16
#define OFF_WP4     50765824ull               // 256 wg * 65536 f16
#define OFF_WP0     84320256ull               // 256 wg * 16384 f16
#define OFF_EMBW    92708864ull               // [32000][1024] f16
#define OFF_WIN     158244864ull              // [1024][1024] f16
#define OFF_WOUT    160342016ull              // [1024][2048] f16
#define OFF_ENC     164536320ull              // [64][32][1024] f16
#define OFF_H2ALL   168730624ull              // [4096][1024] f16
#define OFF_CONCAT  177119232ull              // [4096][2048] f16
#define OFF_TARGET  193896448ull              // [4096][1024] f16
#define OFF_HT      202285056ull              // [4096][1024] f16
#define WS_NEEDED   210673664ull

// ---------------- f32 -> f16 convert (vectorized, grid-stride) ----------------
__global__ __launch_bounds__(256) void k_conv(const float* __restrict__ s,
                                              _Float16* __restrict__ d, int n4) {
  int i = blockIdx.x * blockDim.x + threadIdx.x;
  int st = gridDim.x * blockDim.x;
  for (; i < n4; i += st) {
    float4 v = ((const float4*)s)[i];
    h16x4 o; o[0] = (_Float16)v.x; o[1] = (_Float16)v.y; o[2] = (_Float16)v.z; o[3] = (_Float16)v.w;
    ((h16x4*)d)[i] = o;
  }
}

// ---------------- embedding gather -> f16 ----------------
__global__ __launch_bounds__(256) void k_gather(const int* __restrict__ tok,
                                                const float* __restrict__ embW,
                                                _Float16* __restrict__ emb) {
  int row = blockIdx.x;                 // row = t*32+b
  int t = tok[row];
  float4 v = ((const float4*)(embW + (size_t)t * EE))[threadIdx.x];
  h16x4 o; o[0] = (_Float16)v.x; o[1] = (_Float16)v.y; o[2] = (_Float16)v.z; o[3] = (_Float16)v.w;
  ((h16x4*)(emb + (size_t)row * EE))[threadIdx.x] = o;
}

// ---------------- pack 4 LDS-resident matrices (Wih1,Whh1,Wih2,Whh2) ----------------
// Wpack4[w][mat][jj][k_lds] = W[layer][row(w,jj)][k_lds ^ ((jj&7)<<3)]  (XOR pre-swizzle)
__global__ __launch_bounds__(256) void k_packw4(const float* __restrict__ Wih,
                                                const float* __restrict__ Whh,
                                                _Float16* __restrict__ out) {
  int i = blockIdx.x * blockDim.x + threadIdx.x;
  int st = gridDim.x * blockDim.x;
  const int total = 256 * 65536;
  for (; i < total; i += st) {
    int w = i >> 16, rem = i & 65535;
    int mat = rem >> 14, jj = (rem >> 10) & 15, k = rem & 1023;
    int layer = 1 + (mat >> 1), isHH = mat & 1;
    int row = ((jj >> 2) << 10) + (w << 2) + (jj & 3);
    int ks = k ^ ((jj & 7) << 3);
    const float* src = (isHH ? Whh : Wih) + (size_t)layer * G4 * 1024 + (size_t)row * 1024 + ks;
    out[i] = (_Float16)(*src);
  }
}

// ---------------- pack Whh0 fragment-linear: [w][ks 0..31][lane 0..63][e 0..7] ----------------
__global__ __launch_bounds__(256) void k_packw0(const float* __restrict__ Whh,
                                                _Float16* __restrict__ out) {
  int i = blockIdx.x * blockDim.x + threadIdx.x;
  int st = gridDim.x * blockDim.x;
  const int total = 256 * 16384;
  for (; i < total; i += st) {
    int w = i >> 14, rem = i & 16383;
    int ks = rem >> 9, lane = (rem >> 3) & 63, e = rem & 7;
    int jj = lane & 15, q = lane >> 4;
    int row = ((jj >> 2) << 10) + (w << 2) + (jj & 3);
    int k = ks * 32 + q * 8 + e;
    out[i] = (_Float16)Whh[(size_t)row * 1024 + k];   // layer 0
  }
}

// ---------------- init: sync flags + initial h fragments ----------------
// parity init per layer: l0 -> slot[0][1], l1 -> slot[1][0], l2 -> slot[2][1]
__global__ __launch_bounds__(256) void k_init(const float* __restrict__ h0,
                                              _Float16* __restrict__ hfrag,
                                              unsigned* __restrict__ sync) {
  int i = blockIdx.x * blockDim.x + threadIdx.x;
  if (i < 64 + 8192 + 256) sync[i] = 0u;   // pad + arrive (strided) + summary
  if (i >= 3 * BB * HH) return;
  int l = i >> 15, rem = i & 32767;
  int b = rem >> 10, n = rem & 1023;
  int parI = (l == 1) ? 0 : 1;
  int tbb = b >> 4, ks = n >> 5, q = (n >> 3) & 3, e = n & 7;
  int lane2 = (b & 15) | (q << 4);
  hfrag[(size_t)(l * 2 + parI) * 32768 + ((size_t)(tbb * 32 + ks) * 64 + lane2) * 8 + e] =
      (_Float16)h0[i];
}

// ---------------- generic 128x128 BT GEMM (A[M,K] f16, B[N,K] f16) ----------------
// staging via global_load_lds width=16; XCD-aware block swizzle (grid % 8 == 0)
// EPI: 0 = f32 + bias1 ; 1 = f16 ; 2 = f16(tanh) ; 3 = f16 + bias1 + bias2
template <int EPI>
__global__ __launch_bounds__(256) void k_gemm(const _Float16* __restrict__ A,
                                              const _Float16* __restrict__ B,
                                              void* __restrict__ C, int M, int N, int K,
                                              const float* __restrict__ bias1,
                                              const float* __restrict__ bias2) {
  __shared__ _Float16 As[2][128 * 32];
  __shared__ _Float16 Bs[2][128 * 32];
  const int ntn = N / 128;
  // bijective XCD swizzle: consecutive blocks within an XCD share the A panel
  const int nwg = gridDim.x;
  const int bid = (blockIdx.x & 7) * (nwg >> 3) + (blockIdx.x >> 3);
  const int tm = bid / ntn, tn = bid % ntn;
  const int tid = threadIdx.x, lane = tid & 63;
  const int wv = tid >> 6, wr = wv >> 1, wc = wv & 1;
  f32x4 acc[4][4] = {};

  auto stage = [&](int buf, int k0) {
#pragma unroll
    for (int i = 0; i < 2; ++i) {
      int eo = (i * 256 + tid) * 8;
      int r = eo >> 5, c = eo & 31;
      __builtin_amdgcn_global_load_lds(AS_G(A + (size_t)(tm * 128 + r) * K + k0 + c),
                                       AS_L(&As[buf][eo]), 16, 0, 0);
      __builtin_amdgcn_global_load_lds(AS_G(B + (size_t)(tn * 128 + r) * K + k0 + c),
                                       AS_L(&Bs[buf][eo]), 16, 0, 0);
    }
  };
  stage(0, 0);
  __syncthreads();
  const int nk = K / 32;
  for (int kt = 0; kt < nk; ++kt) {
    if (kt + 1 < nk) stage((kt + 1) & 1, (kt + 1) * 32);
    const int buf = kt & 1;
    h16x8 af[4], bfr[4];
#pragma unroll
    for (int mi = 0; mi < 4; ++mi)
      af[mi] = *(const h16x8*)&As[buf][(wr * 64 + mi * 16 + (lane & 15)) * 32 + (lane >> 4) * 8];
#pragma unroll
    for (int ni = 0; ni < 4; ++ni)
      bfr[ni] = *(const h16x8*)&Bs[buf][(wc * 64 + ni * 16 + (lane & 15)) * 32 + (lane >> 4) * 8];
#pragma unroll
    for (int mi = 0; mi < 4; ++mi)
#pragma unroll
      for (int ni = 0; ni < 4; ++ni)
        acc[mi][ni] = __builtin_amdgcn_mfma_f32_16x16x32_f16(af[mi], bfr[ni], acc[mi][ni], 0, 0, 0);
    __syncthreads();
  }
  const int rbase = tm * 128 + wr * 64;
  const int cbase = tn * 128 + wc * 64;
#pragma unroll
  for (int mi = 0; mi < 4; ++mi) {
#pragma unroll
    for (int ni = 0; ni < 4; ++ni) {
#pragma unroll
      for (int r = 0; r < 4; ++r) {
        int mm = rbase + mi * 16 + (lane >> 4) * 4 + r;
        int nn = cbase + ni * 16 + (lane & 15);
        float v = acc[mi][ni][r];
        if (EPI == 0) {
          ((float*)C)[(size_t)mm * N + nn] = v + bias1[nn];
        } else if (EPI == 1) {
          ((_Float16*)C)[(size_t)mm * N + nn] = (_Float16)v;
        } else if (EPI == 2) {
          ((_Float16*)C)[(size_t)mm * N + nn] = (_Float16)tanhf(v);
        } else {
          ((_Float16*)C)[(size_t)mm * N + nn] = (_Float16)(v + bias1[nn] + bias2[nn]);
        }
      }
    }
  }
}

// ---------------- persistent pipelined LSTM recurrence ----------------
// 256 wgs x 512 thr. wg w owns hidden units n = 4w..4w+3 (16 gate rows).
// Tick tau: l0 computes h0(tau), l1 computes h1(tau-1), l2 computes h2(tau-2).
// Exchange: h via agent-scope (sc1) 8B stores from WAVE 0 only; per-wave vmcnt(0)
// orders them before the (relaxed, strided-line) arrive flag. Hierarchical wait:
// 8 group leaders poll 32 member flags each -> summary[g]; all wgs poll the 8
// summaries (28x less poll fan-in than flat). Acquire fence (inv, no writeback),
// then cached h reads (L2-amortized per XCD).
// Regular launch; co-residency structural: 152KB LDS => 1 wg/CU, grid 256 == CU count.
__global__ __launch_bounds__(512) void k_recur(const _Float16* __restrict__ Wp4,
                                               const _Float16* __restrict__ Wp0,
                                               const _Float16* __restrict__ X0bf,
                                               _Float16* __restrict__ hfrag,
                                               _Float16* __restrict__ h2all,
                                               _Float16* __restrict__ concat,
                                               const float* __restrict__ bih,
                                               const float* __restrict__ bhh,
                                               const float* __restrict__ c0p,
                                               unsigned* __restrict__ sync) {
  extern __shared__ char lds[];
  _Float16* ldsW = (_Float16*)lds;                 // 65536 f16
  float* redbuf = (float*)(lds + 131072);          // [3][3][2][256]
  _Float16* hstage = (_Float16*)(lds + 131072);    // [3][128] (reused after redbuf)
  float* gbuf = (float*)(lds + 149504);            // [3][32][16]
  unsigned* arrive = sync + 64;                    // strided: arrive[w*32]
  unsigned* summary = sync + 64 + 8192;            // strided: summary[g*32]

  const int w = blockIdx.x;
  const int tid = threadIdx.x, lane = tid & 63, wv = tid >> 6;
  const int tb = wv & 1, kq = wv >> 1;
  const int row = (lane >> 4) * 4, col = lane & 15;

  // preload LDS weights (linear copy; swizzle pre-applied by k_packw4)
  for (int i = 0; i < 16; ++i) {
    int eo = (i * 512 + tid) * 8;
    *(h16x8*)&ldsW[eo] = *(const h16x8*)(Wp4 + (size_t)w * 65536 + eo);
  }
  // Whh0 fragments in registers
  h16x8 w0reg[8];
#pragma unroll
  for (int i = 0; i < 8; ++i)
    w0reg[i] = *(const h16x8*)(Wp0 + (size_t)w * 16384 + ((size_t)(kq * 8 + i) * 64 + lane) * 8);

  // per-thread epilogue state (threads 0..127 own (b, ni))
  const int eb = tid >> 2, eni = tid & 3, en = w * 4 + eni;
  float c0r = 0.f, c1r = 0.f, c2r = 0.f;
  float b1r[4] = {0, 0, 0, 0}, b2r[4] = {0, 0, 0, 0};
  if (tid < 128) {
    c0r = c0p[0 * BB * HH + eb * HH + en];
    c1r = c0p[1 * BB * HH + eb * HH + en];
    c2r = c0p[2 * BB * HH + eb * HH + en];
#pragma unroll
    for (int g = 0; g < 4; ++g) {
      b1r[g] = bih[1 * G4 + g * 1024 + en] + bhh[1 * G4 + g * 1024 + en];
      b2r[g] = bih[2 * G4 + g * 1024 + en] + bhh[2 * G4 + g * 1024 + en];
    }
  }
  // pack constants (wave 0): run r covers batch row pr = lane&31; 8B per run
  const int pr = lane & 31;
  const size_t pk_idx = ((size_t)(((pr >> 4) * 32 + (w >> 3)) * 64 + (pr & 15) +
                                  (((w >> 1) & 3) << 4))) * 8 + 4 * (w & 1);
  __syncthreads();

  for (int tau = 0; tau < 130; ++tau) {
    const int p = tau & 1;
    const _Float16* h0r = hfrag + (size_t)(0 + (1 - p)) * 32768;
    const _Float16* h1r = hfrag + (size_t)(2 + (1 - p)) * 32768;
    const _Float16* h2r = hfrag + (size_t)(4 + (1 - p)) * 32768;

    // A fragments (coalesced 16B/lane); inactive-layer reads feed discarded accs
    h16x8 a0[8], a1[8], a2[8];
#pragma unroll
    for (int i = 0; i < 8; ++i) {
      int ks = kq * 8 + i;
      size_t off = ((size_t)(tb * 32 + ks) * 64 + lane) * 8;
      a0[i] = *(const h16x8*)(h0r + off);
      a1[i] = *(const h16x8*)(h1r + off);
      a2[i] = *(const h16x8*)(h2r + off);
    }
    // hoist X0 gate loads: LLC latency hides under fragment loads + MFMA
    float xg0 = 0.f, xg1 = 0.f, xg2 = 0.f, xg3 = 0.f;
    if (tid < 128 && tau < 128) {
      size_t xb = ((size_t)(tau * BB + eb)) * G4 + en;
      xg0 = (float)X0bf[xb];        xg1 = (float)X0bf[xb + 1024];
      xg2 = (float)X0bf[xb + 2048]; xg3 = (float)X0bf[xb + 3072];
    }
    f32x4 acc0 = {}, acc1 = {}, acc2 = {};
#pragma unroll
    for (int i = 0; i < 8; ++i) {
      int ks = kq * 8 + i;
      int jj = lane & 15, q = lane >> 4;
      int kk = (ks * 32 + q * 8) ^ ((jj & 7) << 3);
      const h16x8 bw1i = *(const h16x8*)&ldsW[0 * 16384 + jj * 1024 + kk];
      const h16x8 bw1h = *(const h16x8*)&ldsW[1 * 16384 + jj * 1024 + kk];
      const h16x8 bw2i = *(const h16x8*)&ldsW[2 * 16384 + jj * 1024 + kk];
      const h16x8 bw2h = *(const h16x8*)&ldsW[3 * 16384 + jj * 1024 + kk];
      acc0 = __builtin_amdgcn_mfma_f32_16x16x32_f16(a0[i], w0reg[i], acc0, 0, 0, 0);
      acc1 = __builtin_amdgcn_mfma_f32_16x16x32_f16(a0[i], bw1i, acc1, 0, 0, 0);
      acc1 = __builtin_amdgcn_mfma_f32_16x16x32_f16(a1[i], bw1h, acc1, 0, 0, 0);
      acc2 = __builtin_amdgcn_mfma_f32_16x16x32_f16(a1[i], bw2i, acc2, 0, 0, 0);
      acc2 = __builtin_amdgcn_mfma_f32_16x16x32_f16(a2[i], bw2h, acc2, 0, 0, 0);
    }
    // cross-wave K reduction
    if (kq >= 1) {
      int s = kq - 1;
#pragma unroll
      for (int r = 0; r < 4; ++r) {
        redbuf[((0 * 3 + s) * 2 + tb) * 256 + (row + r) * 16 + col] = acc0[r];
        redbuf[((1 * 3 + s) * 2 + tb) * 256 + (row + r) * 16 + col] = acc1[r];
        redbuf[((2 * 3 + s) * 2 + tb) * 256 + (row + r) * 16 + col] = acc2[r];
      }
    }
    __syncthreads();
    if (kq == 0) {
#pragma unroll
      for (int r = 0; r < 4; ++r) {
        float v0 = acc0[r], v1 = acc1[r], v2 = acc2[r];
#pragma unroll
        for (int s = 0; s < 3; ++s) {
          v0 += redbuf[((0 * 3 + s) * 2 + tb) * 256 + (row + r) * 16 + col];
          v1 += redbuf[((1 * 3 + s) * 2 + tb) * 256 + (row + r) * 16 + col];
          v2 += redbuf[((2 * 3 + s) * 2 + tb) * 256 + (row + r) * 16 + col];
        }
        gbuf[(0 * 32 + tb * 16 + row + r) * 16 + col] = v0;
        gbuf[(1 * 32 + tb * 16 + row + r) * 16 + col] = v1;
        gbuf[(2 * 32 + tb * 16 + row + r) * 16 + col] = v2;
      }
    }
    __syncthreads();
    // elementwise LSTM epilogue -> hstage (LDS) + h2all/concat (regular stores)
    if (tid < 128) {
      if (tau < 128) {  // layer 0: X0 already holds x@Wih0^T + b_ih0 + b_hh0
        float gi = gbuf[(0 * 32 + eb) * 16 + eni] + xg0;
        float gf = gbuf[(0 * 32 + eb) * 16 + 4 + eni] + xg1;
        float gg = gbuf[(0 * 32 + eb) * 16 + 8 + eni] + xg2;
        float go = gbuf[(0 * 32 + eb) * 16 + 12 + eni] + xg3;
        c0r = sigmf(gf) * c0r + sigmf(gi) * tanhf(gg);
        hstage[0 * 128 + tid] = (_Float16)(sigmf(go) * tanhf(c0r));
      }
      if (tau >= 1 && tau < 129) {  // layer 1
        float gi = gbuf[(1 * 32 + eb) * 16 + eni] + b1r[0];
        float gf = gbuf[(1 * 32 + eb) * 16 + 4 + eni] + b1r[1];
        float gg = gbuf[(1 * 32 + eb) * 16 + 8 + eni] + b1r[2];
        float go = gbuf[(1 * 32 + eb) * 16 + 12 + eni] + b1r[3];
        c1r = sigmf(gf) * c1r + sigmf(gi) * tanhf(gg);
        hstage[1 * 128 + tid] = (_Float16)(sigmf(go) * tanhf(c1r));
      }
      if (tau >= 2) {  // layer 2
        float gi = gbuf[(2 * 32 + eb) * 16 + eni] + b2r[0];
        float gf = gbuf[(2 * 32 + eb) * 16 + 4 + eni] + b2r[1];
        float gg = gbuf[(2 * 32 + eb) * 16 + 8 + eni] + b2r[2];
        float go = gbuf[(2 * 32 + eb) * 16 + 12 + eni] + b2r[3];
        c2r = sigmf(gf) * c2r + sigmf(gi) * tanhf(gg);
        float h = sigmf(go) * tanhf(c2r);
        _Float16 hb = (_Float16)h;
        hstage[2 * 128 + tid] = hb;
        int t2 = tau - 2;
        h2all[(size_t)(t2 * BB + eb) * HH + en] = hb;
        concat[(size_t)(t2 * BB + eb) * 2048 + 1024 + en] = hb;
      }
    }
    __syncthreads();   // hstage visible in LDS
    // wave 0: pack (sc1 8B stores) -> vmcnt(0) [per-WAVE counter] -> flag ->
    //         hierarchical wait -> acquire fence. Other waves go to the barrier.
    if (wv == 0) {
      {  // store for run lane: layer lane>>5 (0 or 1)
        int l0 = lane >> 5;
        bool act0 = (l0 == 0) ? (tau < 128) : (tau >= 1 && tau < 129);
        if (act0) {
          unsigned long long v = *(const unsigned long long*)&hstage[l0 * 128 + pr * 4];
          __hip_atomic_store(
              (unsigned long long*)(hfrag + (size_t)(l0 * 2 + p) * 32768 + pk_idx), v,
              __ATOMIC_RELAXED, __HIP_MEMORY_SCOPE_AGENT);
        }
        if (lane < 32 && tau >= 2) {  // run lane+64: layer 2
          unsigned long long v = *(const unsigned long long*)&hstage[2 * 128 + pr * 4];
          __hip_atomic_store(
              (unsigned long long*)(hfrag + (size_t)(4 + p) * 32768 + pk_idx), v,
              __ATOMIC_RELAXED, __HIP_MEMORY_SCOPE_AGENT);
        }
      }
      asm volatile("s_waitcnt vmcnt(0)" ::: "memory");   // wave's sc1 stores at LLC
      if (lane == 0)
        __hip_atomic_store(&arrive[w * 32], (unsigned)(tau + 1), __ATOMIC_RELAXED,
                           __HIP_MEMORY_SCOPE_AGENT);
      if (tau < 129) {   // last tick: no one consumes, skip the wait
        const unsigned tgt = (unsigned)(tau + 1);
        if ((w & 31) == 0) {   // group leader: poll my 32 member flags
          for (;;) {
            bool ok = true;
            if (lane < 32) {
              unsigned v = __hip_atomic_load(&arrive[(w + lane) * 32], __ATOMIC_RELAXED,
                                             __HIP_MEMORY_SCOPE_AGENT);
              ok = (v >= tgt);
            }
            if (__all(ok)) break;
            __builtin_amdgcn_s_sleep(1);
          }
          if (lane == 0)
            __hip_atomic_store(&summary[(w >> 5) * 32], tgt, __ATOMIC_RELAXED,
                               __HIP_MEMORY_SCOPE_AGENT);
        }
        for (;;) {   // everyone: poll the 8 group summaries
          bool ok = true;
          if (lane < 8) {
            unsigned v = __hip_atomic_load(&summary[lane * 32], __ATOMIC_RELAXED,
                                           __HIP_MEMORY_SCOPE_AGENT);
            ok = (v >= tgt);
          }
          if (__all(ok)) break;
          __builtin_amdgcn_s_sleep(1);
        }
        __builtin_amdgcn_fence(__ATOMIC_ACQUIRE, "agent");  // inv L1/L2, no writeback
      }
    }
    __syncthreads();
  }
}

// ---------------- fused scores+softmax+weighted-context per (t,b) ----------------
__global__ __launch_bounds__(256) void k_attn(const _Float16* __restrict__ target,
                                              const _Float16* __restrict__ encb,
                                              _Float16* __restrict__ concat) {
  __shared__ float sc[64];
  __shared__ float att[64];
  int m = blockIdx.x, b = m & 31;
  int tid = threadIdx.x, lane = tid & 63, wv = tid >> 6;
  const h16x8* tp = (const h16x8*)(target + (size_t)m * EE + lane * 16);
  h16x8 tg0 = tp[0], tg1 = tp[1];
  for (int si = 0; si < 16; ++si) {
    int s = wv * 16 + si;
    const h16x8* ep = (const h16x8*)(encb + ((size_t)s * BB + b) * EE + lane * 16);
    h16x8 e0 = ep[0], e1 = ep[1];
    float a = 0.f;
#pragma unroll
    for (int j = 0; j < 8; ++j) a += (float)e0[j] * (float)tg0[j];
#pragma unroll
    for (int j = 0; j < 8; ++j) a += (float)e1[j] * (float)tg1[j];
#pragma unroll
    for (int off = 32; off >= 1; off >>= 1) a += __shfl_xor(a, off);
    if (lane == 0) sc[s] = a;
  }
  __syncthreads();
  if (wv == 0) {
    float v = sc[lane], mx = v;
#pragma unroll
    for (int off = 32; off >= 1; off >>= 1) mx = fmaxf(mx, __shfl_xor(mx, off));
    float e = expf(v - mx), sm = e;
#pragma unroll
    for (int off = 32; off >= 1; off >>= 1) sm += __shfl_xor(sm, off);
    att[lane] = e / sm;
  }
  __syncthreads();
  int e4 = tid * 4;
  float a0 = 0, a1 = 0, a2 = 0, a3 = 0;
  for (int s = 0; s < 64; ++s) {
    float wgt = att[s];
    h16x4 ev = *(const h16x4*)(encb + ((size_t)s * BB + b) * EE + e4);
    a0 += wgt * (float)ev[0]; a1 += wgt * (float)ev[1];
    a2 += wgt * (float)ev[2]; a3 += wgt * (float)ev[3];
  }
  h16x4 o; o[0] = (_Float16)a0; o[1] = (_Float16)a1; o[2] = (_Float16)a2; o[3] = (_Float16)a3;
  *(h16x4*)(concat + (size_t)m * 2048 + e4) = o;
}

// ---------------- host ----------------
extern "C" void kernel_launch(void* const* d_in, const int* in_sizes, int n_in,
                              void* d_out, int out_size, void* d_ws, size_t ws_size,
                              hipStream_t stream) {
  const int* tokens = (const int*)d_in[0];
  const float* embW = (const float*)d_in[1];
  const float* Wih = (const float*)d_in[2];
  const float* Whh = (const float*)d_in[3];
  const float* bih = (const float*)d_in[4];
  const float* bhh = (const float*)d_in[5];
  const float* Win = (const float*)d_in[6];
  const float* Wout = (const float*)d_in[7];
  const float* finalb = (const float*)d_in[8];
  const float* enc = (const float*)d_in[9];
  const float* h0 = (const float*)d_in[10];
  const float* c0 = (const float*)d_in[11];
  (void)in_sizes; (void)n_in; (void)out_size;
  if (ws_size < WS_NEEDED) return;

  char* ws = (char*)d_ws;
  unsigned* sync = (unsigned*)(ws + OFF_SYNC);
  _Float16* hfrag = (_Float16*)(ws + OFF_HFRAG);
  _Float16* emb = (_Float16*)(ws + OFF_EMB);
  _Float16* X0bf = (_Float16*)(ws + OFF_X0);
  _Float16* Wih0b = (_Float16*)(ws + OFF_WIH0);
  _Float16* Wp4 = (_Float16*)(ws + OFF_WP4);
  _Float16* Wp0 = (_Float16*)(ws + OFF_WP0);
  _Float16* embWb = (_Float16*)(ws + OFF_EMBW);
  _Float16* Winb = (_Float16*)(ws + OFF_WIN);
  _Float16* Woutb = (_Float16*)(ws + OFF_WOUT);
  _Float16* encb = (_Float16*)(ws + OFF_ENC);
  _Float16* h2all = (_Float16*)(ws + OFF_H2ALL);
  _Float16* concat = (_Float16*)(ws + OFF_CONCAT);
  _Float16* target = (_Float16*)(ws + OFF_TARGET);
  _Float16* ht = (_Float16*)(ws + OFF_HT);

  const unsigned LDSB = 155648;  // 128KB weights + 18KB redbuf + 6KB gbuf
  static int lds_set = 0;
  if (!lds_set) {
    hipFuncSetAttribute((const void*)k_recur, hipFuncAttributeMaxDynamicSharedMemorySize,
                        (int)LDSB);
    lds_set = 1;   // attribute is sticky on the function; setting once is enough
  }

  // prep: converts / packs / init
  k_conv<<<4096, 256, 0, stream>>>(embW, embWb, VV * EE / 4);
  k_conv<<<1024, 256, 0, stream>>>(Wih, Wih0b, G4 * EE / 4);       // layer-0 W_ih
  k_conv<<<512, 256, 0, stream>>>(Win, Winb, EE * EE / 4);
  k_conv<<<512, 256, 0, stream>>>(Wout, Woutb, EE * 2048 / 4);
  k_conv<<<512, 256, 0, stream>>>(enc, encb, 64 * BB * EE / 4);
  k_gather<<<NROWS, 256, 0, stream>>>(tokens, embW, emb);
  k_packw4<<<8192, 256, 0, stream>>>(Wih, Whh, Wp4);
  k_packw0<<<4096, 256, 0, stream>>>(Whh, Wp0);
  k_init<<<384, 256, 0, stream>>>(h0, hfrag, sync);

  // X0 = emb @ Wih0^T + b_ih0 + b_hh0   -> f16 [4096,4096]
  k_gemm<3><<<32 * 32, 256, 0, stream>>>(emb, Wih0b, X0bf, NROWS, G4, EE, bih, bhh);

  // recurrence: REGULAR launch (graph-capturable); co-residency structural
  k_recur<<<256, 512, LDSB, stream>>>(Wp4, Wp0, X0bf, hfrag, h2all, concat,
                                      bih, bhh, c0, sync);

  // attention chain
  k_gemm<1><<<32 * 8, 256, 0, stream>>>(h2all, Winb, target, NROWS, EE, EE, nullptr, nullptr);
  k_attn<<<NROWS, 256, 0, stream>>>(target, encb, concat);
  k_gemm<2><<<32 * 8, 256, 0, stream>>>(concat, Woutb, ht, NROWS, EE, 2048, nullptr, nullptr);

  // logits = ht @ embW^T + final_b  -> f32 d_out
  k_gemm<0><<<32 * 250, 256, 0, stream>>>(ht, embWb, d_out, NROWS, VV, EE, finalb, nullptr);
}

// Round 8
// 1697.479 us; speedup vs baseline: 1.1799x; 1.0357x over previous
//
#include <hip/hip_runtime.h>
#include <cstdint>
#include <cstddef>

#define SEQ   128
#define BB    32
#define EE    1024
#define HH    1024
#define G4    4096
#define VV    32000
#define NROWS 4096   // SEQ*BB

typedef _Float16 h16x8 __attribute__((ext_vector_type(8)));
typedef _Float16 h16x4 __attribute__((ext_vector_type(4)));
typedef float f32x4  __attribute__((ext_vector_type(4)));

#define AS_G(p) ((const __attribute__((address_space(1))) void*)(p))
#define AS_L(p) ((__attribute__((address_space(3))) void*)(p))

__device__ __forceinline__ float sigmf(float x) { return 1.0f / (1.0f + expf(-x)); }

// ---------------- ws layout (bytes) ----------------
// sync region (40960 B): pad[64] dwords @0; arrive[256] strided 128B @dword 64.
#define OFF_SYNC    0ull
#define OFF_HFRAG   40960ull                  // 6 slots * 32768 f16 = 393216 B
#define OFF_EMB     434176ull                 // [4096][1024] f16
#define OFF_X0      8822784ull                // [4096][4096] f16
#define OFF_WIH0    42377216ull               // [4096][1024] f16
#define OFF_WP4     50765824ull               // 256 wg * 65536 f16
#define OFF_WP0     84320256ull               // 256 wg * 16384 f16
#define OFF_EMBW    92708864ull               // [32000][1024] f16
#define OFF_WIN     158244864ull              // [1024][1024] f16
#define OFF_WOUT    160342016ull              // [1024][2048] f16
#define OFF_ENC     164536320ull              // [64][32][1024] f16
#define OFF_H2ALL   168730624ull              // [4096][1024] f16
#define OFF_CONCAT  177119232ull              // [4096][2048] f16
#define OFF_TARGET  193896448ull              // [4096][1024] f16
#define OFF_HT      202285056ull              // [4096][1024] f16
#define WS_NEEDED   210673664ull

// ---------------- f32 -> f16 convert (vectorized, grid-stride) ----------------
__global__ __launch_bounds__(256) void k_conv(const float* __restrict__ s,
                                              _Float16* __restrict__ d, int n4) {
  int i = blockIdx.x * blockDim.x + threadIdx.x;
  int st = gridDim.x * blockDim.x;
  for (; i < n4; i += st) {
    float4 v = ((const float4*)s)[i];
    h16x4 o; o[0] = (_Float16)v.x; o[1] = (_Float16)v.y; o[2] = (_Float16)v.z; o[3] = (_Float16)v.w;
    ((h16x4*)d)[i] = o;
  }
}

// ---------------- embedding gather -> f16 ----------------
__global__ __launch_bounds__(256) void k_gather(const int* __restrict__ tok,
                                                const float* __restrict__ embW,
                                                _Float16* __restrict__ emb) {
  int row = blockIdx.x;                 // row = t*32+b
  int t = tok[row];
  float4 v = ((const float4*)(embW + (size_t)t * EE))[threadIdx.x];
  h16x4 o; o[0] = (_Float16)v.x; o[1] = (_Float16)v.y; o[2] = (_Float16)v.z; o[3] = (_Float16)v.w;
  ((h16x4*)(emb + (size_t)row * EE))[threadIdx.x] = o;
}

// ---------------- pack 4 LDS-resident matrices (Wih1,Whh1,Wih2,Whh2) ----------------
// Wpack4[w][mat][jj][k_lds] = W[layer][row(w,jj)][k_lds ^ ((jj&7)<<3)]  (XOR pre-swizzle)
__global__ __launch_bounds__(256) void k_packw4(const float* __restrict__ Wih,
                                                const float* __restrict__ Whh,
                                                _Float16* __restrict__ out) {
  int i = blockIdx.x * blockDim.x + threadIdx.x;
  int st = gridDim.x * blockDim.x;
  const int total = 256 * 65536;
  for (; i < total; i += st) {
    int w = i >> 16, rem = i & 65535;
    int mat = rem >> 14, jj = (rem >> 10) & 15, k = rem & 1023;
    int layer = 1 + (mat >> 1), isHH = mat & 1;
    int row = ((jj >> 2) << 10) + (w << 2) + (jj & 3);
    int ks = k ^ ((jj & 7) << 3);
    const float* src = (isHH ? Whh : Wih) + (size_t)layer * G4 * 1024 + (size_t)row * 1024 + ks;
    out[i] = (_Float16)(*src);
  }
}

// ---------------- pack Whh0 fragment-linear: [w][ks 0..31][lane 0..63][e 0..7] ----------------
__global__ __launch_bounds__(256) void k_packw0(const float* __restrict__ Whh,
                                                _Float16* __restrict__ out) {
  int i = blockIdx.x * blockDim.x + threadIdx.x;
  int st = gridDim.x * blockDim.x;
  const int total = 256 * 16384;
  for (; i < total; i += st) {
    int w = i >> 14, rem = i & 16383;
    int ks = rem >> 9, lane = (rem >> 3) & 63, e = rem & 7;
    int jj = lane & 15, q = lane >> 4;
    int row = ((jj >> 2) << 10) + (w << 2) + (jj & 3);
    int k = ks * 32 + q * 8 + e;
    out[i] = (_Float16)Whh[(size_t)row * 1024 + k];   // layer 0
  }
}

// ---------------- init: sync flags + initial h fragments ----------------
// parity init per layer: l0 -> slot[0][1], l1 -> slot[1][0], l2 -> slot[2][1]
__global__ __launch_bounds__(256) void k_init(const float* __restrict__ h0,
                                              _Float16* __restrict__ hfrag,
                                              unsigned* __restrict__ sync) {
  int i = blockIdx.x * blockDim.x + threadIdx.x;
  if (i < 64 + 8192) sync[i] = 0u;   // pad + arrive (strided)
  if (i >= 3 * BB * HH) return;
  int l = i >> 15, rem = i & 32767;
  int b = rem >> 10, n = rem & 1023;
  int parI = (l == 1) ? 0 : 1;
  int tbb = b >> 4, ks = n >> 5, q = (n >> 3) & 3, e = n & 7;
  int lane2 = (b & 15) | (q << 4);
  hfrag[(size_t)(l * 2 + parI) * 32768 + ((size_t)(tbb * 32 + ks) * 64 + lane2) * 8 + e] =
      (_Float16)h0[i];
}

// ---------------- generic 128x128 BT GEMM (A[M,K] f16, B[N,K] f16) ----------------
// staging via global_load_lds width=16; XCD-aware block swizzle (grid % 8 == 0)
// EPI: 0 = f32 + bias1 ; 1 = f16 ; 2 = f16(tanh) ; 3 = f16 + bias1 + bias2
template <int EPI>
__global__ __launch_bounds__(256) void k_gemm(const _Float16* __restrict__ A,
                                              const _Float16* __restrict__ B,
                                              void* __restrict__ C, int M, int N, int K,
                                              const float* __restrict__ bias1,
                                              const float* __restrict__ bias2) {
  __shared__ _Float16 As[2][128 * 32];
  __shared__ _Float16 Bs[2][128 * 32];
  const int ntn = N / 128;
  // bijective XCD swizzle: consecutive blocks within an XCD share the A panel
  const int nwg = gridDim.x;
  const int bid = (blockIdx.x & 7) * (nwg >> 3) + (blockIdx.x >> 3);
  const int tm = bid / ntn, tn = bid % ntn;
  const int tid = threadIdx.x, lane = tid & 63;
  const int wv = tid >> 6, wr = wv >> 1, wc = wv & 1;
  f32x4 acc[4][4] = {};

  auto stage = [&](int buf, int k0) {
#pragma unroll
    for (int i = 0; i < 2; ++i) {
      int eo = (i * 256 + tid) * 8;
      int r = eo >> 5, c = eo & 31;
      __builtin_amdgcn_global_load_lds(AS_G(A + (size_t)(tm * 128 + r) * K + k0 + c),
                                       AS_L(&As[buf][eo]), 16, 0, 0);
      __builtin_amdgcn_global_load_lds(AS_G(B + (size_t)(tn * 128 + r) * K + k0 + c),
                                       AS_L(&Bs[buf][eo]), 16, 0, 0);
    }
  };
  stage(0, 0);
  __syncthreads();
  const int nk = K / 32;
  for (int kt = 0; kt < nk; ++kt) {
    if (kt + 1 < nk) stage((kt + 1) & 1, (kt + 1) * 32);
    const int buf = kt & 1;
    h16x8 af[4], bfr[4];
#pragma unroll
    for (int mi = 0; mi < 4; ++mi)
      af[mi] = *(const h16x8*)&As[buf][(wr * 64 + mi * 16 + (lane & 15)) * 32 + (lane >> 4) * 8];
#pragma unroll
    for (int ni = 0; ni < 4; ++ni)
      bfr[ni] = *(const h16x8*)&Bs[buf][(wc * 64 + ni * 16 + (lane & 15)) * 32 + (lane >> 4) * 8];
#pragma unroll
    for (int mi = 0; mi < 4; ++mi)
#pragma unroll
      for (int ni = 0; ni < 4; ++ni)
        acc[mi][ni] = __builtin_amdgcn_mfma_f32_16x16x32_f16(af[mi], bfr[ni], acc[mi][ni], 0, 0, 0);
    __syncthreads();
  }
  const int rbase = tm * 128 + wr * 64;
  const int cbase = tn * 128 + wc * 64;
#pragma unroll
  for (int mi = 0; mi < 4; ++mi) {
#pragma unroll
    for (int ni = 0; ni < 4; ++ni) {
#pragma unroll
      for (int r = 0; r < 4; ++r) {
        int mm = rbase + mi * 16 + (lane >> 4) * 4 + r;
        int nn = cbase + ni * 16 + (lane & 15);
        float v = acc[mi][ni][r];
        if (EPI == 0) {
          ((float*)C)[(size_t)mm * N + nn] = v + bias1[nn];
        } else if (EPI == 1) {
          ((_Float16*)C)[(size_t)mm * N + nn] = (_Float16)v;
        } else if (EPI == 2) {
          ((_Float16*)C)[(size_t)mm * N + nn] = (_Float16)tanhf(v);
        } else {
          ((_Float16*)C)[(size_t)mm * N + nn] = (_Float16)(v + bias1[nn] + bias2[nn]);
        }
      }
    }
  }
}

// ---------------- persistent pipelined LSTM recurrence ----------------
// 256 wgs x 512 thr. wg w owns hidden units n = 4w..4w+3 (16 gate rows).
// Tick tau: l0 computes h0(tau), l1 computes h1(tau-1), l2 computes h2(tau-2).
// Exchange protocol = R5-proven: h via agent-scope (sc1) 8B stores (96 thr),
// all-wave vmcnt(0) + barrier, tid0 relaxed flag (own 128B line), 64-lane x4
// strided poll with s_sleep backoff, acquire fence (inv only), cached h reads.
// Regular launch; co-residency structural: 152KB LDS => 1 wg/CU, grid 256 == CU count.
__global__ __launch_bounds__(512) void k_recur(const _Float16* __restrict__ Wp4,
                                               const _Float16* __restrict__ Wp0,
                                               const _Float16* __restrict__ X0bf,
                                               _Float16* __restrict__ hfrag,
                                               _Float16* __restrict__ h2all,
                                               _Float16* __restrict__ concat,
                                               const float* __restrict__ bih,
                                               const float* __restrict__ bhh,
                                               const float* __restrict__ c0p,
                                               unsigned* __restrict__ sync) {
  extern __shared__ char lds[];
  _Float16* ldsW = (_Float16*)lds;                 // 65536 f16
  float* redbuf = (float*)(lds + 131072);          // [3][3][2][256]
  _Float16* hstage = (_Float16*)(lds + 131072);    // [3][128] (reused after redbuf)
  float* gbuf = (float*)(lds + 149504);            // [3][32][16]
  unsigned* arrive = sync + 64;                    // strided: arrive[w*32]

  const int w = blockIdx.x;
  const int tid = threadIdx.x, lane = tid & 63, wv = tid >> 6;
  const int tb = wv & 1, kq = wv >> 1;
  const int row = (lane >> 4) * 4, col = lane & 15;

  // preload LDS weights (linear copy; swizzle pre-applied by k_packw4)
  for (int i = 0; i < 16; ++i) {
    int eo = (i * 512 + tid) * 8;
    *(h16x8*)&ldsW[eo] = *(const h16x8*)(Wp4 + (size_t)w * 65536 + eo);
  }
  // Whh0 fragments in registers
  h16x8 w0reg[8];
#pragma unroll
  for (int i = 0; i < 8; ++i)
    w0reg[i] = *(const h16x8*)(Wp0 + (size_t)w * 16384 + ((size_t)(kq * 8 + i) * 64 + lane) * 8);

  // per-thread epilogue state (threads 0..127 own (b, ni))
  const int eb = tid >> 2, eni = tid & 3, en = w * 4 + eni;
  float c0r = 0.f, c1r = 0.f, c2r = 0.f;
  float b1r[4] = {0, 0, 0, 0}, b2r[4] = {0, 0, 0, 0};
  if (tid < 128) {
    c0r = c0p[0 * BB * HH + eb * HH + en];
    c1r = c0p[1 * BB * HH + eb * HH + en];
    c2r = c0p[2 * BB * HH + eb * HH + en];
#pragma unroll
    for (int g = 0; g < 4; ++g) {
      b1r[g] = bih[1 * G4 + g * 1024 + en] + bhh[1 * G4 + g * 1024 + en];
      b2r[g] = bih[2 * G4 + g * 1024 + en] + bhh[2 * G4 + g * 1024 + en];
    }
  }
  // pack-phase constants: thread (pk_l, pk_r) stores layer pk_l, batch row pk_r
  const int pk_l = tid >> 5, pk_r = tid & 31;
  const size_t pk_idx = ((size_t)(((pk_r >> 4) * 32 + (w >> 3)) * 64 + (pk_r & 15) +
                                  (((w >> 1) & 3) << 4))) * 8 + 4 * (w & 1);
  __syncthreads();

  for (int tau = 0; tau < 130; ++tau) {
    const int p = tau & 1;
    const _Float16* h0r = hfrag + (size_t)(0 + (1 - p)) * 32768;
    const _Float16* h1r = hfrag + (size_t)(2 + (1 - p)) * 32768;
    const _Float16* h2r = hfrag + (size_t)(4 + (1 - p)) * 32768;

    // A fragments (coalesced 16B/lane); inactive-layer reads feed discarded accs
    h16x8 a0[8], a1[8], a2[8];
#pragma unroll
    for (int i = 0; i < 8; ++i) {
      int ks = kq * 8 + i;
      size_t off = ((size_t)(tb * 32 + ks) * 64 + lane) * 8;
      a0[i] = *(const h16x8*)(h0r + off);
      a1[i] = *(const h16x8*)(h1r + off);
      a2[i] = *(const h16x8*)(h2r + off);
    }
    // hoist X0 gate loads: LLC latency hides under fragment loads + MFMA
    float xg0 = 0.f, xg1 = 0.f, xg2 = 0.f, xg3 = 0.f;
    if (tid < 128 && tau < 128) {
      size_t xb = ((size_t)(tau * BB + eb)) * G4 + en;
      xg0 = (float)X0bf[xb];        xg1 = (float)X0bf[xb + 1024];
      xg2 = (float)X0bf[xb + 2048]; xg3 = (float)X0bf[xb + 3072];
    }
    f32x4 acc0 = {}, acc1 = {}, acc2 = {};
#pragma unroll
    for (int i = 0; i < 8; ++i) {
      int ks = kq * 8 + i;
      int jj = lane & 15, q = lane >> 4;
      int kk = (ks * 32 + q * 8) ^ ((jj & 7) << 3);
      const h16x8 bw1i = *(const h16x8*)&ldsW[0 * 16384 + jj * 1024 + kk];
      const h16x8 bw1h = *(const h16x8*)&ldsW[1 * 16384 + jj * 1024 + kk];
      const h16x8 bw2i = *(const h16x8*)&ldsW[2 * 16384 + jj * 1024 + kk];
      const h16x8 bw2h = *(const h16x8*)&ldsW[3 * 16384 + jj * 1024 + kk];
      acc0 = __builtin_amdgcn_mfma_f32_16x16x32_f16(a0[i], w0reg[i], acc0, 0, 0, 0);
      acc1 = __builtin_amdgcn_mfma_f32_16x16x32_f16(a0[i], bw1i, acc1, 0, 0, 0);
      acc1 = __builtin_amdgcn_mfma_f32_16x16x32_f16(a1[i], bw1h, acc1, 0, 0, 0);
      acc2 = __builtin_amdgcn_mfma_f32_16x16x32_f16(a1[i], bw2i, acc2, 0, 0, 0);
      acc2 = __builtin_amdgcn_mfma_f32_16x16x32_f16(a2[i], bw2h, acc2, 0, 0, 0);
    }
    // cross-wave K reduction
    if (kq >= 1) {
      int s = kq - 1;
#pragma unroll
      for (int r = 0; r < 4; ++r) {
        redbuf[((0 * 3 + s) * 2 + tb) * 256 + (row + r) * 16 + col] = acc0[r];
        redbuf[((1 * 3 + s) * 2 + tb) * 256 + (row + r) * 16 + col] = acc1[r];
        redbuf[((2 * 3 + s) * 2 + tb) * 256 + (row + r) * 16 + col] = acc2[r];
      }
    }
    __syncthreads();
    if (kq == 0) {
#pragma unroll
      for (int r = 0; r < 4; ++r) {
        float v0 = acc0[r], v1 = acc1[r], v2 = acc2[r];
#pragma unroll
        for (int s = 0; s < 3; ++s) {
          v0 += redbuf[((0 * 3 + s) * 2 + tb) * 256 + (row + r) * 16 + col];
          v1 += redbuf[((1 * 3 + s) * 2 + tb) * 256 + (row + r) * 16 + col];
          v2 += redbuf[((2 * 3 + s) * 2 + tb) * 256 + (row + r) * 16 + col];
        }
        gbuf[(0 * 32 + tb * 16 + row + r) * 16 + col] = v0;
        gbuf[(1 * 32 + tb * 16 + row + r) * 16 + col] = v1;
        gbuf[(2 * 32 + tb * 16 + row + r) * 16 + col] = v2;
      }
    }
    __syncthreads();
    // elementwise LSTM epilogue -> hstage (LDS) + h2all/concat (regular stores)
    if (tid < 128) {
      if (tau < 128) {  // layer 0: X0 already holds x@Wih0^T + b_ih0 + b_hh0
        float gi = gbuf[(0 * 32 + eb) * 16 + eni] + xg0;
        float gf = gbuf[(0 * 32 + eb) * 16 + 4 + eni] + xg1;
        float gg = gbuf[(0 * 32 + eb) * 16 + 8 + eni] + xg2;
        float go = gbuf[(0 * 32 + eb) * 16 + 12 + eni] + xg3;
        c0r = sigmf(gf) * c0r + sigmf(gi) * tanhf(gg);
        hstage[0 * 128 + tid] = (_Float16)(sigmf(go) * tanhf(c0r));
      }
      if (tau >= 1 && tau < 129) {  // layer 1
        float gi = gbuf[(1 * 32 + eb) * 16 + eni] + b1r[0];
        float gf = gbuf[(1 * 32 + eb) * 16 + 4 + eni] + b1r[1];
        float gg = gbuf[(1 * 32 + eb) * 16 + 8 + eni] + b1r[2];
        float go = gbuf[(1 * 32 + eb) * 16 + 12 + eni] + b1r[3];
        c1r = sigmf(gf) * c1r + sigmf(gi) * tanhf(gg);
        hstage[1 * 128 + tid] = (_Float16)(sigmf(go) * tanhf(c1r));
      }
      if (tau >= 2) {  // layer 2
        float gi = gbuf[(2 * 32 + eb) * 16 + eni] + b2r[0];
        float gf = gbuf[(2 * 32 + eb) * 16 + 4 + eni] + b2r[1];
        float gg = gbuf[(2 * 32 + eb) * 16 + 8 + eni] + b2r[2];
        float go = gbuf[(2 * 32 + eb) * 16 + 12 + eni] + b2r[3];
        c2r = sigmf(gf) * c2r + sigmf(gi) * tanhf(gg);
        float h = sigmf(go) * tanhf(c2r);
        _Float16 hb = (_Float16)h;
        hstage[2 * 128 + tid] = hb;
        int t2 = tau - 2;
        h2all[(size_t)(t2 * BB + eb) * HH + en] = hb;
        concat[(size_t)(t2 * BB + eb) * 2048 + 1024 + en] = hb;
      }
    }
    __syncthreads();   // hstage visible in LDS
    // pack phase (R5 protocol): 96 threads emit one 8B agent-scope (sc1) store
    {
      bool act = (tid < 96) &&
                 ((pk_l == 0) ? (tau < 128)
                  : (pk_l == 1) ? (tau >= 1 && tau < 129) : (tau >= 2));
      if (act) {
        unsigned long long v = *(const unsigned long long*)&hstage[pk_l * 128 + pk_r * 4];
        __hip_atomic_store(
            (unsigned long long*)(hfrag + (size_t)(pk_l * 2 + p) * 32768 + pk_idx), v,
            __ATOMIC_RELAXED, __HIP_MEMORY_SCOPE_AGENT);
      }
      asm volatile("s_waitcnt vmcnt(0)" ::: "memory");   // own sc1 stores at LLC
    }
    __syncthreads();   // all pack stores complete before flag
    if (tid == 0)
      __hip_atomic_store(&arrive[w * 32], (unsigned)(tau + 1), __ATOMIC_RELAXED,
                         __HIP_MEMORY_SCOPE_AGENT);
    if (tau < 129) {   // last tick: no one consumes, skip the wait
      if (tid < 64) {
        for (;;) {
          bool ok = true;
#pragma unroll
          for (int j = 0; j < 4; ++j) {
            unsigned v = __hip_atomic_load(&arrive[(tid * 4 + j) * 32], __ATOMIC_RELAXED,
                                           __HIP_MEMORY_SCOPE_AGENT);
            ok &= (v >= (unsigned)(tau + 1));
          }
          if (__all(ok)) break;
          __builtin_amdgcn_s_sleep(1);
        }
        __builtin_amdgcn_fence(__ATOMIC_ACQUIRE, "agent");  // inv L1/L2, no writeback
      }
      __syncthreads();
    }
  }
}

// ---------------- fused scores+softmax+weighted-context per (t,b) ----------------
__global__ __launch_bounds__(256) void k_attn(const _Float16* __restrict__ target,
                                              const _Float16* __restrict__ encb,
                                              _Float16* __restrict__ concat) {
  __shared__ float sc[64];
  __shared__ float att[64];
  int m = blockIdx.x, b = m & 31;
  int tid = threadIdx.x, lane = tid & 63, wv = tid >> 6;
  const h16x8* tp = (const h16x8*)(target + (size_t)m * EE + lane * 16);
  h16x8 tg0 = tp[0], tg1 = tp[1];
  for (int si = 0; si < 16; ++si) {
    int s = wv * 16 + si;
    const h16x8* ep = (const h16x8*)(encb + ((size_t)s * BB + b) * EE + lane * 16);
    h16x8 e0 = ep[0], e1 = ep[1];
    float a = 0.f;
#pragma unroll
    for (int j = 0; j < 8; ++j) a += (float)e0[j] * (float)tg0[j];
#pragma unroll
    for (int j = 0; j < 8; ++j) a += (float)e1[j] * (float)tg1[j];
#pragma unroll
    for (int off = 32; off >= 1; off >>= 1) a += __shfl_xor(a, off);
    if (lane == 0) sc[s] = a;
  }
  __syncthreads();
  if (wv == 0) {
    float v = sc[lane], mx = v;
#pragma unroll
    for (int off = 32; off >= 1; off >>= 1) mx = fmaxf(mx, __shfl_xor(mx, off));
    float e = expf(v - mx), sm = e;
#pragma unroll
    for (int off = 32; off >= 1; off >>= 1) sm += __shfl_xor(sm, off);
    att[lane] = e / sm;
  }
  __syncthreads();
  int e4 = tid * 4;
  float a0 = 0, a1 = 0, a2 = 0, a3 = 0;
  for (int s = 0; s < 64; ++s) {
    float wgt = att[s];
    h16x4 ev = *(const h16x4*)(encb + ((size_t)s * BB + b) * EE + e4);
    a0 += wgt * (float)ev[0]; a1 += wgt * (float)ev[1];
    a2 += wgt * (float)ev[2]; a3 += wgt * (float)ev[3];
  }
  h16x4 o; o[0] = (_Float16)a0; o[1] = (_Float16)a1; o[2] = (_Float16)a2; o[3] = (_Float16)a3;
  *(h16x4*)(concat + (size_t)m * 2048 + e4) = o;
}

// ---------------- host ----------------
extern "C" void kernel_launch(void* const* d_in, const int* in_sizes, int n_in,
                              void* d_out, int out_size, void* d_ws, size_t ws_size,
                              hipStream_t stream) {
  const int* tokens = (const int*)d_in[0];
  const float* embW = (const float*)d_in[1];
  const float* Wih = (const float*)d_in[2];
  const float* Whh = (const float*)d_in[3];
  const float* bih = (const float*)d_in[4];
  const float* bhh = (const float*)d_in[5];
  const float* Win = (const float*)d_in[6];
  const float* Wout = (const float*)d_in[7];
  const float* finalb = (const float*)d_in[8];
  const float* enc = (const float*)d_in[9];
  const float* h0 = (const float*)d_in[10];
  const float* c0 = (const float*)d_in[11];
  (void)in_sizes; (void)n_in; (void)out_size;
  if (ws_size < WS_NEEDED) return;

  char* ws = (char*)d_ws;
  unsigned* sync = (unsigned*)(ws + OFF_SYNC);
  _Float16* hfrag = (_Float16*)(ws + OFF_HFRAG);
  _Float16* emb = (_Float16*)(ws + OFF_EMB);
  _Float16* X0bf = (_Float16*)(ws + OFF_X0);
  _Float16* Wih0b = (_Float16*)(ws + OFF_WIH0);
  _Float16* Wp4 = (_Float16*)(ws + OFF_WP4);
  _Float16* Wp0 = (_Float16*)(ws + OFF_WP0);
  _Float16* embWb = (_Float16*)(ws + OFF_EMBW);
  _Float16* Winb = (_Float16*)(ws + OFF_WIN);
  _Float16* Woutb = (_Float16*)(ws + OFF_WOUT);
  _Float16* encb = (_Float16*)(ws + OFF_ENC);
  _Float16* h2all = (_Float16*)(ws + OFF_H2ALL);
  _Float16* concat = (_Float16*)(ws + OFF_CONCAT);
  _Float16* target = (_Float16*)(ws + OFF_TARGET);
  _Float16* ht = (_Float16*)(ws + OFF_HT);

  const unsigned LDSB = 155648;  // 128KB weights + 18KB redbuf + 6KB gbuf
  static int lds_set = 0;
  if (!lds_set) {
    hipFuncSetAttribute((const void*)k_recur, hipFuncAttributeMaxDynamicSharedMemorySize,
                        (int)LDSB);
    lds_set = 1;   // attribute is sticky on the function; setting once is enough
  }

  // prep: converts / packs / init
  k_conv<<<4096, 256, 0, stream>>>(embW, embWb, VV * EE / 4);
  k_conv<<<1024, 256, 0, stream>>>(Wih, Wih0b, G4 * EE / 4);       // layer-0 W_ih
  k_conv<<<512, 256, 0, stream>>>(Win, Winb, EE * EE / 4);
  k_conv<<<512, 256, 0, stream>>>(Wout, Woutb, EE * 2048 / 4);
  k_conv<<<512, 256, 0, stream>>>(enc, encb, 64 * BB * EE / 4);
  k_gather<<<NROWS, 256, 0, stream>>>(tokens, embW, emb);
  k_packw4<<<8192, 256, 0, stream>>>(Wih, Whh, Wp4);
  k_packw0<<<4096, 256, 0, stream>>>(Whh, Wp0);
  k_init<<<384, 256, 0, stream>>>(h0, hfrag, sync);

  // X0 = emb @ Wih0^T + b_ih0 + b_hh0   -> f16 [4096,4096]
  k_gemm<3><<<32 * 32, 256, 0, stream>>>(emb, Wih0b, X0bf, NROWS, G4, EE, bih, bhh);

  // recurrence: REGULAR launch (graph-capturable); co-residency structural
  k_recur<<<256, 512, LDSB, stream>>>(Wp4, Wp0, X0bf, hfrag, h2all, concat,
                                      bih, bhh, c0, sync);

  // attention chain
  k_gemm<1><<<32 * 8, 256, 0, stream>>>(h2all, Winb, target, NROWS, EE, EE, nullptr, nullptr);
  k_attn<<<NROWS, 256, 0, stream>>>(target, encb, concat);
  k_gemm<2><<<32 * 8, 256, 0, stream>>>(concat, Woutb, ht, NROWS, EE, 2048, nullptr, nullptr);

  // logits = ht @ embW^T + final_b  -> f32 d_out
  k_gemm<0><<<32 * 250, 256, 0, stream>>>(ht, embWb, d_out, NROWS, VV, EE, finalb, nullptr);
}

// Round 9
// 1637.207 us; speedup vs baseline: 1.2233x; 1.0368x over previous
//
#include <hip/hip_runtime.h>
#include <cstdint>
#include <cstddef>

#define SEQ   128
#define BB    32
#define EE    1024
#define HH    1024
#define G4    4096
#define VV    32000
#define NROWS 4096   // SEQ*BB

typedef _Float16 h16x8 __attribute__((ext_vector_type(8)));
typedef _Float16 h16x4 __attribute__((ext_vector_type(4)));
typedef float f32x4  __attribute__((ext_vector_type(4)));

#define AS_G(p) ((const __attribute__((address_space(1))) void*)(p))
#define AS_L(p) ((__attribute__((address_space(3))) void*)(p))

__device__ __forceinline__ float sigmf(float x) { return 1.0f / (1.0f + expf(-x)); }

// ---------------- ws layout (bytes) ----------------
// sync region (40960 B): pad[64] dwords @0; arrive[256] strided 128B @dword 64.
#define OFF_SYNC    0ull
#define OFF_HFRAG   40960ull                  // 6 slots * 32768 f16 = 393216 B
#define OFF_EMB     434176ull                 // [4096][1024] f16
#define OFF_X0      8822784ull                // [4096][4096] f16
#define OFF_WIH0    42377216ull               // [4096][1024] f16
#define OFF_WP4     50765824ull               // 256 wg * 65536 f16
#define OFF_WP0     84320256ull               // 256 wg * 16384 f16
#define OFF_EMBW    92708864ull               // [32000][1024] f16
#define OFF_WIN     158244864ull              // [1024][1024] f16
#define OFF_WOUT    160342016ull              // [1024][2048] f16
#define OFF_ENC     164536320ull              // [64][32][1024] f16
#define OFF_H2ALL   168730624ull              // [4096][1024] f16
#define OFF_CONCAT  177119232ull              // [4096][2048] f16
#define OFF_TARGET  193896448ull              // [4096][1024] f16
#define OFF_HT      202285056ull              // [4096][1024] f16
#define WS_NEEDED   210673664ull

// ---------------- f32 -> f16 convert (vectorized, grid-stride) ----------------
__global__ __launch_bounds__(256) void k_conv(const float* __restrict__ s,
                                              _Float16* __restrict__ d, int n4) {
  int i = blockIdx.x * blockDim.x + threadIdx.x;
  int st = gridDim.x * blockDim.x;
  for (; i < n4; i += st) {
    float4 v = ((const float4*)s)[i];
    h16x4 o; o[0] = (_Float16)v.x; o[1] = (_Float16)v.y; o[2] = (_Float16)v.z; o[3] = (_Float16)v.w;
    ((h16x4*)d)[i] = o;
  }
}

// ---------------- embedding gather -> f16 ----------------
__global__ __launch_bounds__(256) void k_gather(const int* __restrict__ tok,
                                                const float* __restrict__ embW,
                                                _Float16* __restrict__ emb) {
  int row = blockIdx.x;                 // row = t*32+b
  int t = tok[row];
  float4 v = ((const float4*)(embW + (size_t)t * EE))[threadIdx.x];
  h16x4 o; o[0] = (_Float16)v.x; o[1] = (_Float16)v.y; o[2] = (_Float16)v.z; o[3] = (_Float16)v.w;
  ((h16x4*)(emb + (size_t)row * EE))[threadIdx.x] = o;
}

// ---------------- pack 4 LDS-resident matrices (Wih1,Whh1,Wih2,Whh2) ----------------
// Wpack4[w][mat][jj][k_lds] = W[layer][row(w,jj)][k_lds ^ ((jj&7)<<3)]  (XOR pre-swizzle)
__global__ __launch_bounds__(256) void k_packw4(const float* __restrict__ Wih,
                                                const float* __restrict__ Whh,
                                                _Float16* __restrict__ out) {
  int i = blockIdx.x * blockDim.x + threadIdx.x;
  int st = gridDim.x * blockDim.x;
  const int total = 256 * 65536;
  for (; i < total; i += st) {
    int w = i >> 16, rem = i & 65535;
    int mat = rem >> 14, jj = (rem >> 10) & 15, k = rem & 1023;
    int layer = 1 + (mat >> 1), isHH = mat & 1;
    int row = ((jj >> 2) << 10) + (w << 2) + (jj & 3);
    int ks = k ^ ((jj & 7) << 3);
    const float* src = (isHH ? Whh : Wih) + (size_t)layer * G4 * 1024 + (size_t)row * 1024 + ks;
    out[i] = (_Float16)(*src);
  }
}

// ---------------- pack Whh0 fragment-linear: [w][ks 0..31][lane 0..63][e 0..7] ----------------
__global__ __launch_bounds__(256) void k_packw0(const float* __restrict__ Whh,
                                                _Float16* __restrict__ out) {
  int i = blockIdx.x * blockDim.x + threadIdx.x;
  int st = gridDim.x * blockDim.x;
  const int total = 256 * 16384;
  for (; i < total; i += st) {
    int w = i >> 14, rem = i & 16383;
    int ks = rem >> 9, lane = (rem >> 3) & 63, e = rem & 7;
    int jj = lane & 15, q = lane >> 4;
    int row = ((jj >> 2) << 10) + (w << 2) + (jj & 3);
    int k = ks * 32 + q * 8 + e;
    out[i] = (_Float16)Whh[(size_t)row * 1024 + k];   // layer 0
  }
}

// ---------------- init: sync flags + initial h fragments ----------------
// parity init per layer: l0 -> slot[0][1], l1 -> slot[1][0], l2 -> slot[2][1]
__global__ __launch_bounds__(256) void k_init(const float* __restrict__ h0,
                                              _Float16* __restrict__ hfrag,
                                              unsigned* __restrict__ sync) {
  int i = blockIdx.x * blockDim.x + threadIdx.x;
  if (i < 64 + 8192) sync[i] = 0u;   // pad + arrive (strided)
  if (i >= 3 * BB * HH) return;
  int l = i >> 15, rem = i & 32767;
  int b = rem >> 10, n = rem & 1023;
  int parI = (l == 1) ? 0 : 1;
  int tbb = b >> 4, ks = n >> 5, q = (n >> 3) & 3, e = n & 7;
  int lane2 = (b & 15) | (q << 4);
  hfrag[(size_t)(l * 2 + parI) * 32768 + ((size_t)(tbb * 32 + ks) * 64 + lane2) * 8 + e] =
      (_Float16)h0[i];
}

// ---------------- generic 128x128 BT GEMM (A[M,K] f16, B[N,K] f16) ----------------
// staging via global_load_lds width=16; XCD-aware block swizzle (grid % 8 == 0)
// EPI: 1 = f16 ; 2 = f16(tanh)   (big GEMMs use k_gemm256)
template <int EPI>
__global__ __launch_bounds__(256) void k_gemm(const _Float16* __restrict__ A,
                                              const _Float16* __restrict__ B,
                                              void* __restrict__ C, int M, int N, int K,
                                              const float* __restrict__ bias1,
                                              const float* __restrict__ bias2) {
  __shared__ _Float16 As[2][128 * 32];
  __shared__ _Float16 Bs[2][128 * 32];
  const int ntn = N / 128;
  const int nwg = gridDim.x;
  const int bid = (blockIdx.x & 7) * (nwg >> 3) + (blockIdx.x >> 3);
  const int tm = bid / ntn, tn = bid % ntn;
  const int tid = threadIdx.x, lane = tid & 63;
  const int wv = tid >> 6, wr = wv >> 1, wc = wv & 1;
  f32x4 acc[4][4] = {};

  auto stage = [&](int buf, int k0) {
#pragma unroll
    for (int i = 0; i < 2; ++i) {
      int eo = (i * 256 + tid) * 8;
      int r = eo >> 5, c = eo & 31;
      __builtin_amdgcn_global_load_lds(AS_G(A + (size_t)(tm * 128 + r) * K + k0 + c),
                                       AS_L(&As[buf][eo]), 16, 0, 0);
      __builtin_amdgcn_global_load_lds(AS_G(B + (size_t)(tn * 128 + r) * K + k0 + c),
                                       AS_L(&Bs[buf][eo]), 16, 0, 0);
    }
  };
  stage(0, 0);
  __syncthreads();
  const int nk = K / 32;
  for (int kt = 0; kt < nk; ++kt) {
    if (kt + 1 < nk) stage((kt + 1) & 1, (kt + 1) * 32);
    const int buf = kt & 1;
    h16x8 af[4], bfr[4];
#pragma unroll
    for (int mi = 0; mi < 4; ++mi)
      af[mi] = *(const h16x8*)&As[buf][(wr * 64 + mi * 16 + (lane & 15)) * 32 + (lane >> 4) * 8];
#pragma unroll
    for (int ni = 0; ni < 4; ++ni)
      bfr[ni] = *(const h16x8*)&Bs[buf][(wc * 64 + ni * 16 + (lane & 15)) * 32 + (lane >> 4) * 8];
#pragma unroll
    for (int mi = 0; mi < 4; ++mi)
#pragma unroll
      for (int ni = 0; ni < 4; ++ni)
        acc[mi][ni] = __builtin_amdgcn_mfma_f32_16x16x32_f16(af[mi], bfr[ni], acc[mi][ni], 0, 0, 0);
    __syncthreads();
  }
  const int rbase = tm * 128 + wr * 64;
  const int cbase = tn * 128 + wc * 64;
#pragma unroll
  for (int mi = 0; mi < 4; ++mi) {
#pragma unroll
    for (int ni = 0; ni < 4; ++ni) {
#pragma unroll
      for (int r = 0; r < 4; ++r) {
        int mm = rbase + mi * 16 + (lane >> 4) * 4 + r;
        int nn = cbase + ni * 16 + (lane & 15);
        float v = acc[mi][ni][r];
        if (EPI == 1) {
          ((_Float16*)C)[(size_t)mm * N + nn] = (_Float16)v;
        } else {
          ((_Float16*)C)[(size_t)mm * N + nn] = (_Float16)tanhf(v);
        }
      }
    }
  }
}

// ---------------- 256x256 BT GEMM, 3-slot LDS ring + counted vmcnt (T4) ----------------
// BK=32; 512 thr = 8 waves (2 Mwaves x 4 Nwaves); wave tile 128x64 (8x4 frags).
// Steady state: stage tile t+2 (4 loads), s_waitcnt vmcnt(4) (tile t+1 landed,
// t+2 in flight ACROSS the barrier - no drain), raw s_barrier, ds_read, MFMA,
// raw s_barrier. BK=32's 64B row stride spreads b128 frag reads over all 32
// banks (8 groups x 8 lanes = 8-cyc floor) - no swizzle needed.
// EPI: 0 = f32 + bias1 ; 1 = f16 + bias1 + bias2
template <int EPI>
__global__ __launch_bounds__(512, 2) void k_gemm256(const _Float16* __restrict__ A,
                                                    const _Float16* __restrict__ B,
                                                    void* __restrict__ C, int M, int N, int K,
                                                    const float* __restrict__ bias1,
                                                    const float* __restrict__ bias2) {
  extern __shared__ char glds[];
  _Float16* Asl = (_Float16*)glds;                     // [3][256*32]
  _Float16* Bsl = (_Float16*)(glds + 3 * 8192 * 2);    // [3][256*32]
  const int ntn = N / 256;
  const int nwg = gridDim.x;
  const int bid = (blockIdx.x & 7) * (nwg >> 3) + (blockIdx.x >> 3);
  const int tm = bid / ntn, tn = bid % ntn;
  const int tid = threadIdx.x, lane = tid & 63;
  const int wid = tid >> 6, wm = wid >> 2, wn = wid & 3;
  const int fr = lane & 15, fc = lane >> 4;
  const int srow0 = tid >> 2, sg = tid & 3;    // staging: row within 128-half, granule

  f32x4 acc[8][4] = {};
  const int nt = K / 32;

  auto stage = [&](int t) {
    const int slot = t % 3;
    const size_t kof = (size_t)t * 32 + sg * 8;
#pragma unroll
    for (int r = 0; r < 2; ++r) {
      int row = r * 128 + srow0;
      __builtin_amdgcn_global_load_lds(AS_G(A + (size_t)(tm * 256 + row) * K + kof),
                                       AS_L(&Asl[slot * 8192 + row * 32 + sg * 8]), 16, 0, 0);
    }
#pragma unroll
    for (int r = 0; r < 2; ++r) {
      int row = r * 128 + srow0;
      __builtin_amdgcn_global_load_lds(AS_G(B + (size_t)(tn * 256 + row) * K + kof),
                                       AS_L(&Bsl[slot * 8192 + row * 32 + sg * 8]), 16, 0, 0);
    }
  };

  stage(0);
  stage(1);
  asm volatile("s_waitcnt vmcnt(4)" ::: "memory");   // tile 0 landed (mine)
  asm volatile("s_barrier" ::: "memory");            // tile 0 landed (all waves)

  for (int t = 0; t < nt; ++t) {
    if (t + 2 < nt) {
      stage(t + 2);
      asm volatile("s_waitcnt vmcnt(4)" ::: "memory");   // tile t+1 landed; t+2 in flight
    } else {
      asm volatile("s_waitcnt vmcnt(0)" ::: "memory");   // tail drain
    }
    asm volatile("s_barrier" ::: "memory");              // globalize tile t+1 / protect ring
    const int slot = t % 3;
    const _Float16* as = &Asl[slot * 8192];
    const _Float16* bs = &Bsl[slot * 8192];
    h16x8 af[8], bf[4];
#pragma unroll
    for (int mi = 0; mi < 8; ++mi)
      af[mi] = *(const h16x8*)&as[(wm * 128 + mi * 16 + fr) * 32 + fc * 8];
#pragma unroll
    for (int ni = 0; ni < 4; ++ni)
      bf[ni] = *(const h16x8*)&bs[(wn * 64 + ni * 16 + fr) * 32 + fc * 8];
    __builtin_amdgcn_s_setprio(1);
#pragma unroll
    for (int mi = 0; mi < 8; ++mi)
#pragma unroll
      for (int ni = 0; ni < 4; ++ni)
        acc[mi][ni] = __builtin_amdgcn_mfma_f32_16x16x32_f16(af[mi], bf[ni], acc[mi][ni], 0, 0, 0);
    __builtin_amdgcn_s_setprio(0);
    asm volatile("s_barrier" ::: "memory");   // my reads of slot done before others restage it
  }

  const int rbase = tm * 256 + wm * 128;
  const int cbase = tn * 256 + wn * 64;
#pragma unroll
  for (int mi = 0; mi < 8; ++mi) {
#pragma unroll
    for (int ni = 0; ni < 4; ++ni) {
#pragma unroll
      for (int r = 0; r < 4; ++r) {
        int mm = rbase + mi * 16 + fc * 4 + r;
        int nn = cbase + ni * 16 + fr;
        float v = acc[mi][ni][r];
        if (EPI == 0) {
          ((float*)C)[(size_t)mm * N + nn] = v + bias1[nn];
        } else {
          ((_Float16*)C)[(size_t)mm * N + nn] = (_Float16)(v + bias1[nn] + bias2[nn]);
        }
      }
    }
  }
}

// ---------------- persistent pipelined LSTM recurrence ----------------
// 256 wgs x 512 thr. wg w owns hidden units n = 4w..4w+3 (16 gate rows).
// Tick tau: l0 computes h0(tau), l1 computes h1(tau-1), l2 computes h2(tau-2).
// Exchange protocol = R5-proven: h via agent-scope (sc1) 8B stores (96 thr),
// all-wave vmcnt(0) + barrier, tid0 relaxed flag (own 128B line), 64-lane x4
// strided poll with s_sleep backoff, acquire fence (inv only), cached h reads.
// Regular launch; co-residency structural: 152KB LDS => 1 wg/CU, grid 256 == CU count.
__global__ __launch_bounds__(512) void k_recur(const _Float16* __restrict__ Wp4,
                                               const _Float16* __restrict__ Wp0,
                                               const _Float16* __restrict__ X0bf,
                                               _Float16* __restrict__ hfrag,
                                               _Float16* __restrict__ h2all,
                                               _Float16* __restrict__ concat,
                                               const float* __restrict__ bih,
                                               const float* __restrict__ bhh,
                                               const float* __restrict__ c0p,
                                               unsigned* __restrict__ sync) {
  extern __shared__ char lds[];
  _Float16* ldsW = (_Float16*)lds;                 // 65536 f16
  float* redbuf = (float*)(lds + 131072);          // [3][3][2][256]
  _Float16* hstage = (_Float16*)(lds + 131072);    // [3][128] (reused after redbuf)
  float* gbuf = (float*)(lds + 149504);            // [3][32][16]
  unsigned* arrive = sync + 64;                    // strided: arrive[w*32]

  const int w = blockIdx.x;
  const int tid = threadIdx.x, lane = tid & 63, wv = tid >> 6;
  const int tb = wv & 1, kq = wv >> 1;
  const int row = (lane >> 4) * 4, col = lane & 15;

  // preload LDS weights (linear copy; swizzle pre-applied by k_packw4)
  for (int i = 0; i < 16; ++i) {
    int eo = (i * 512 + tid) * 8;
    *(h16x8*)&ldsW[eo] = *(const h16x8*)(Wp4 + (size_t)w * 65536 + eo);
  }
  // Whh0 fragments in registers
  h16x8 w0reg[8];
#pragma unroll
  for (int i = 0; i < 8; ++i)
    w0reg[i] = *(const h16x8*)(Wp0 + (size_t)w * 16384 + ((size_t)(kq * 8 + i) * 64 + lane) * 8);

  // per-thread epilogue state (threads 0..127 own (b, ni))
  const int eb = tid >> 2, eni = tid & 3, en = w * 4 + eni;
  float c0r = 0.f, c1r = 0.f, c2r = 0.f;
  float b1r[4] = {0, 0, 0, 0}, b2r[4] = {0, 0, 0, 0};
  if (tid < 128) {
    c0r = c0p[0 * BB * HH + eb * HH + en];
    c1r = c0p[1 * BB * HH + eb * HH + en];
    c2r = c0p[2 * BB * HH + eb * HH + en];
#pragma unroll
    for (int g = 0; g < 4; ++g) {
      b1r[g] = bih[1 * G4 + g * 1024 + en] + bhh[1 * G4 + g * 1024 + en];
      b2r[g] = bih[2 * G4 + g * 1024 + en] + bhh[2 * G4 + g * 1024 + en];
    }
  }
  // pack-phase constants: thread (pk_l, pk_r) stores layer pk_l, batch row pk_r
  const int pk_l = tid >> 5, pk_r = tid & 31;
  const size_t pk_idx = ((size_t)(((pk_r >> 4) * 32 + (w >> 3)) * 64 + (pk_r & 15) +
                                  (((w >> 1) & 3) << 4))) * 8 + 4 * (w & 1);
  __syncthreads();

  for (int tau = 0; tau < 130; ++tau) {
    const int p = tau & 1;
    const _Float16* h0r = hfrag + (size_t)(0 + (1 - p)) * 32768;
    const _Float16* h1r = hfrag + (size_t)(2 + (1 - p)) * 32768;
    const _Float16* h2r = hfrag + (size_t)(4 + (1 - p)) * 32768;

    // A fragments (coalesced 16B/lane); inactive-layer reads feed discarded accs
    h16x8 a0[8], a1[8], a2[8];
#pragma unroll
    for (int i = 0; i < 8; ++i) {
      int ks = kq * 8 + i;
      size_t off = ((size_t)(tb * 32 + ks) * 64 + lane) * 8;
      a0[i] = *(const h16x8*)(h0r + off);
      a1[i] = *(const h16x8*)(h1r + off);
      a2[i] = *(const h16x8*)(h2r + off);
    }
    // hoist X0 gate loads: LLC latency hides under fragment loads + MFMA
    float xg0 = 0.f, xg1 = 0.f, xg2 = 0.f, xg3 = 0.f;
    if (tid < 128 && tau < 128) {
      size_t xb = ((size_t)(tau * BB + eb)) * G4 + en;
      xg0 = (float)X0bf[xb];        xg1 = (float)X0bf[xb + 1024];
      xg2 = (float)X0bf[xb + 2048]; xg3 = (float)X0bf[xb + 3072];
    }
    f32x4 acc0 = {}, acc1 = {}, acc2 = {};
#pragma unroll
    for (int i = 0; i < 8; ++i) {
      int ks = kq * 8 + i;
      int jj = lane & 15, q = lane >> 4;
      int kk = (ks * 32 + q * 8) ^ ((jj & 7) << 3);
      const h16x8 bw1i = *(const h16x8*)&ldsW[0 * 16384 + jj * 1024 + kk];
      const h16x8 bw1h = *(const h16x8*)&ldsW[1 * 16384 + jj * 1024 + kk];
      const h16x8 bw2i = *(const h16x8*)&ldsW[2 * 16384 + jj * 1024 + kk];
      const h16x8 bw2h = *(const h16x8*)&ldsW[3 * 16384 + jj * 1024 + kk];
      acc0 = __builtin_amdgcn_mfma_f32_16x16x32_f16(a0[i], w0reg[i], acc0, 0, 0, 0);
      acc1 = __builtin_amdgcn_mfma_f32_16x16x32_f16(a0[i], bw1i, acc1, 0, 0, 0);
      acc1 = __builtin_amdgcn_mfma_f32_16x16x32_f16(a1[i], bw1h, acc1, 0, 0, 0);
      acc2 = __builtin_amdgcn_mfma_f32_16x16x32_f16(a1[i], bw2i, acc2, 0, 0, 0);
      acc2 = __builtin_amdgcn_mfma_f32_16x16x32_f16(a2[i], bw2h, acc2, 0, 0, 0);
    }
    // cross-wave K reduction
    if (kq >= 1) {
      int s = kq - 1;
#pragma unroll
      for (int r = 0; r < 4; ++r) {
        redbuf[((0 * 3 + s) * 2 + tb) * 256 + (row + r) * 16 + col] = acc0[r];
        redbuf[((1 * 3 + s) * 2 + tb) * 256 + (row + r) * 16 + col] = acc1[r];
        redbuf[((2 * 3 + s) * 2 + tb) * 256 + (row + r) * 16 + col] = acc2[r];
      }
    }
    __syncthreads();
    if (kq == 0) {
#pragma unroll
      for (int r = 0; r < 4; ++r) {
        float v0 = acc0[r], v1 = acc1[r], v2 = acc2[r];
#pragma unroll
        for (int s = 0; s < 3; ++s) {
          v0 += redbuf[((0 * 3 + s) * 2 + tb) * 256 + (row + r) * 16 + col];
          v1 += redbuf[((1 * 3 + s) * 2 + tb) * 256 + (row + r) * 16 + col];
          v2 += redbuf[((2 * 3 + s) * 2 + tb) * 256 + (row + r) * 16 + col];
        }
        gbuf[(0 * 32 + tb * 16 + row + r) * 16 + col] = v0;
        gbuf[(1 * 32 + tb * 16 + row + r) * 16 + col] = v1;
        gbuf[(2 * 32 + tb * 16 + row + r) * 16 + col] = v2;
      }
    }
    __syncthreads();
    // elementwise LSTM epilogue -> hstage (LDS) + h2all/concat (regular stores)
    if (tid < 128) {
      if (tau < 128) {  // layer 0: X0 already holds x@Wih0^T + b_ih0 + b_hh0
        float gi = gbuf[(0 * 32 + eb) * 16 + eni] + xg0;
        float gf = gbuf[(0 * 32 + eb) * 16 + 4 + eni] + xg1;
        float gg = gbuf[(0 * 32 + eb) * 16 + 8 + eni] + xg2;
        float go = gbuf[(0 * 32 + eb) * 16 + 12 + eni] + xg3;
        c0r = sigmf(gf) * c0r + sigmf(gi) * tanhf(gg);
        hstage[0 * 128 + tid] = (_Float16)(sigmf(go) * tanhf(c0r));
      }
      if (tau >= 1 && tau < 129) {  // layer 1
        float gi = gbuf[(1 * 32 + eb) * 16 + eni] + b1r[0];
        float gf = gbuf[(1 * 32 + eb) * 16 + 4 + eni] + b1r[1];
        float gg = gbuf[(1 * 32 + eb) * 16 + 8 + eni] + b1r[2];
        float go = gbuf[(1 * 32 + eb) * 16 + 12 + eni] + b1r[3];
        c1r = sigmf(gf) * c1r + sigmf(gi) * tanhf(gg);
        hstage[1 * 128 + tid] = (_Float16)(sigmf(go) * tanhf(c1r));
      }
      if (tau >= 2) {  // layer 2
        float gi = gbuf[(2 * 32 + eb) * 16 + eni] + b2r[0];
        float gf = gbuf[(2 * 32 + eb) * 16 + 4 + eni] + b2r[1];
        float gg = gbuf[(2 * 32 + eb) * 16 + 8 + eni] + b2r[2];
        float go = gbuf[(2 * 32 + eb) * 16 + 12 + eni] + b2r[3];
        c2r = sigmf(gf) * c2r + sigmf(gi) * tanhf(gg);
        float h = sigmf(go) * tanhf(c2r);
        _Float16 hb = (_Float16)h;
        hstage[2 * 128 + tid] = hb;
        int t2 = tau - 2;
        h2all[(size_t)(t2 * BB + eb) * HH + en] = hb;
        concat[(size_t)(t2 * BB + eb) * 2048 + 1024 + en] = hb;
      }
    }
    __syncthreads();   // hstage visible in LDS
    // pack phase (R5 protocol): 96 threads emit one 8B agent-scope (sc1) store
    {
      bool act = (tid < 96) &&
                 ((pk_l == 0) ? (tau < 128)
                  : (pk_l == 1) ? (tau >= 1 && tau < 129) : (tau >= 2));
      if (act) {
        unsigned long long v = *(const unsigned long long*)&hstage[pk_l * 128 + pk_r * 4];
        __hip_atomic_store(
            (unsigned long long*)(hfrag + (size_t)(pk_l * 2 + p) * 32768 + pk_idx), v,
            __ATOMIC_RELAXED, __HIP_MEMORY_SCOPE_AGENT);
      }
      asm volatile("s_waitcnt vmcnt(0)" ::: "memory");   // own sc1 stores at LLC
    }
    __syncthreads();   // all pack stores complete before flag
    if (tid == 0)
      __hip_atomic_store(&arrive[w * 32], (unsigned)(tau + 1), __ATOMIC_RELAXED,
                         __HIP_MEMORY_SCOPE_AGENT);
    if (tau < 129) {   // last tick: no one consumes, skip the wait
      if (tid < 64) {
        for (;;) {
          bool ok = true;
#pragma unroll
          for (int j = 0; j < 4; ++j) {
            unsigned v = __hip_atomic_load(&arrive[(tid * 4 + j) * 32], __ATOMIC_RELAXED,
                                           __HIP_MEMORY_SCOPE_AGENT);
            ok &= (v >= (unsigned)(tau + 1));
          }
          if (__all(ok)) break;
          __builtin_amdgcn_s_sleep(1);
        }
        __builtin_amdgcn_fence(__ATOMIC_ACQUIRE, "agent");  // inv L1/L2, no writeback
      }
      __syncthreads();
    }
  }
}

// ---------------- fused scores+softmax+weighted-context per (t,b) ----------------
__global__ __launch_bounds__(256) void k_attn(const _Float16* __restrict__ target,
                                              const _Float16* __restrict__ encb,
                                              _Float16* __restrict__ concat) {
  __shared__ float sc[64];
  __shared__ float att[64];
  int m = blockIdx.x, b = m & 31;
  int tid = threadIdx.x, lane = tid & 63, wv = tid >> 6;
  const h16x8* tp = (const h16x8*)(target + (size_t)m * EE + lane * 16);
  h16x8 tg0 = tp[0], tg1 = tp[1];
  for (int si = 0; si < 16; ++si) {
    int s = wv * 16 + si;
    const h16x8* ep = (const h16x8*)(encb + ((size_t)s * BB + b) * EE + lane * 16);
    h16x8 e0 = ep[0], e1 = ep[1];
    float a = 0.f;
#pragma unroll
    for (int j = 0; j < 8; ++j) a += (float)e0[j] * (float)tg0[j];
#pragma unroll
    for (int j = 0; j < 8; ++j) a += (float)e1[j] * (float)tg1[j];
#pragma unroll
    for (int off = 32; off >= 1; off >>= 1) a += __shfl_xor(a, off);
    if (lane == 0) sc[s] = a;
  }
  __syncthreads();
  if (wv == 0) {
    float v = sc[lane], mx = v;
#pragma unroll
    for (int off = 32; off >= 1; off >>= 1) mx = fmaxf(mx, __shfl_xor(mx, off));
    float e = expf(v - mx), sm = e;
#pragma unroll
    for (int off = 32; off >= 1; off >>= 1) sm += __shfl_xor(sm, off);
    att[lane] = e / sm;
  }
  __syncthreads();
  int e4 = tid * 4;
  float a0 = 0, a1 = 0, a2 = 0, a3 = 0;
  for (int s = 0; s < 64; ++s) {
    float wgt = att[s];
    h16x4 ev = *(const h16x4*)(encb + ((size_t)s * BB + b) * EE + e4);
    a0 += wgt * (float)ev[0]; a1 += wgt * (float)ev[1];
    a2 += wgt * (float)ev[2]; a3 += wgt * (float)ev[3];
  }
  h16x4 o; o[0] = (_Float16)a0; o[1] = (_Float16)a1; o[2] = (_Float16)a2; o[3] = (_Float16)a3;
  *(h16x4*)(concat + (size_t)m * 2048 + e4) = o;
}

// ---------------- host ----------------
extern "C" void kernel_launch(void* const* d_in, const int* in_sizes, int n_in,
                              void* d_out, int out_size, void* d_ws, size_t ws_size,
                              hipStream_t stream) {
  const int* tokens = (const int*)d_in[0];
  const float* embW = (const float*)d_in[1];
  const float* Wih = (const float*)d_in[2];
  const float* Whh = (const float*)d_in[3];
  const float* bih = (const float*)d_in[4];
  const float* bhh = (const float*)d_in[5];
  const float* Win = (const float*)d_in[6];
  const float* Wout = (const float*)d_in[7];
  const float* finalb = (const float*)d_in[8];
  const float* enc = (const float*)d_in[9];
  const float* h0 = (const float*)d_in[10];
  const float* c0 = (const float*)d_in[11];
  (void)in_sizes; (void)n_in; (void)out_size;
  if (ws_size < WS_NEEDED) return;

  char* ws = (char*)d_ws;
  unsigned* sync = (unsigned*)(ws + OFF_SYNC);
  _Float16* hfrag = (_Float16*)(ws + OFF_HFRAG);
  _Float16* emb = (_Float16*)(ws + OFF_EMB);
  _Float16* X0bf = (_Float16*)(ws + OFF_X0);
  _Float16* Wih0b = (_Float16*)(ws + OFF_WIH0);
  _Float16* Wp4 = (_Float16*)(ws + OFF_WP4);
  _Float16* Wp0 = (_Float16*)(ws + OFF_WP0);
  _Float16* embWb = (_Float16*)(ws + OFF_EMBW);
  _Float16* Winb = (_Float16*)(ws + OFF_WIN);
  _Float16* Woutb = (_Float16*)(ws + OFF_WOUT);
  _Float16* encb = (_Float16*)(ws + OFF_ENC);
  _Float16* h2all = (_Float16*)(ws + OFF_H2ALL);
  _Float16* concat = (_Float16*)(ws + OFF_CONCAT);
  _Float16* target = (_Float16*)(ws + OFF_TARGET);
  _Float16* ht = (_Float16*)(ws + OFF_HT);

  const unsigned LDSB = 155648;   // k_recur: 128KB weights + 18KB redbuf + 6KB gbuf
  const unsigned LDSG = 98304;    // k_gemm256: 3 slots x (A 16KB + B 16KB)
  static int lds_set = 0;
  if (!lds_set) {
    hipFuncSetAttribute((const void*)k_recur, hipFuncAttributeMaxDynamicSharedMemorySize,
                        (int)LDSB);
    hipFuncSetAttribute((const void*)k_gemm256<0>, hipFuncAttributeMaxDynamicSharedMemorySize,
                        (int)LDSG);
    hipFuncSetAttribute((const void*)k_gemm256<1>, hipFuncAttributeMaxDynamicSharedMemorySize,
                        (int)LDSG);
    lds_set = 1;   // attributes are sticky on the functions
  }

  // prep: converts / packs / init
  k_conv<<<4096, 256, 0, stream>>>(embW, embWb, VV * EE / 4);
  k_conv<<<1024, 256, 0, stream>>>(Wih, Wih0b, G4 * EE / 4);       // layer-0 W_ih
  k_conv<<<512, 256, 0, stream>>>(Win, Winb, EE * EE / 4);
  k_conv<<<512, 256, 0, stream>>>(Wout, Woutb, EE * 2048 / 4);
  k_conv<<<512, 256, 0, stream>>>(enc, encb, 64 * BB * EE / 4);
  k_gather<<<NROWS, 256, 0, stream>>>(tokens, embW, emb);
  k_packw4<<<8192, 256, 0, stream>>>(Wih, Whh, Wp4);
  k_packw0<<<4096, 256, 0, stream>>>(Whh, Wp0);
  k_init<<<384, 256, 0, stream>>>(h0, hfrag, sync);

  // X0 = emb @ Wih0^T + b_ih0 + b_hh0   -> f16 [4096,4096]  (256-tile counted-vmcnt GEMM)
  k_gemm256<1><<<16 * 16, 512, LDSG, stream>>>(emb, Wih0b, X0bf, NROWS, G4, EE, bih, bhh);

  // recurrence: REGULAR launch (graph-capturable); co-residency structural
  k_recur<<<256, 512, LDSB, stream>>>(Wp4, Wp0, X0bf, hfrag, h2all, concat,
                                      bih, bhh, c0, sync);

  // attention chain
  k_gemm<1><<<32 * 8, 256, 0, stream>>>(h2all, Winb, target, NROWS, EE, EE, nullptr, nullptr);
  k_attn<<<NROWS, 256, 0, stream>>>(target, encb, concat);
  k_gemm<2><<<32 * 8, 256, 0, stream>>>(concat, Woutb, ht, NROWS, EE, 2048, nullptr, nullptr);

  // logits = ht @ embW^T + final_b  -> f32 d_out  (256-tile counted-vmcnt GEMM)
  k_gemm256<0><<<16 * 125, 512, LDSG, stream>>>(ht, embWb, d_out, NROWS, VV, EE, finalb, nullptr);
}

// Round 10
// 1452.855 us; speedup vs baseline: 1.3785x; 1.1269x over previous
//
#include <hip/hip_runtime.h>
#include <cstdint>
#include <cstddef>

#define SEQ   128
#define BB    32
#define EE    1024
#define HH    1024
#define G4    4096
#define VV    32000
#define NROWS 4096   // SEQ*BB

typedef _Float16 h16x8 __attribute__((ext_vector_type(8)));
typedef _Float16 h16x4 __attribute__((ext_vector_type(4)));
typedef float f32x4  __attribute__((ext_vector_type(4)));

#define AS_G(p) ((const __attribute__((address_space(1))) void*)(p))
#define AS_L(p) ((__attribute__((address_space(3))) void*)(p))

__device__ __forceinline__ float sigmf(float x) { return 1.0f / (1.0f + expf(-x)); }

// 16B load that bypasses L1+L2 (LLC-coherent with sc1 stores). Batched; caller
// must s_waitcnt vmcnt(0) before use.
__device__ __forceinline__ f32x4 llc_load16(const void* p) {
  f32x4 r;
  asm volatile("global_load_dwordx4 %0, %1, off sc0 sc1" : "=v"(r) : "v"(p) : "memory");
  return r;
}

// ---------------- ws layout (bytes) ----------------
// sync region (40960 B): pad[64] dwords @0; arrive[256] strided 128B @dword 64.
#define OFF_SYNC    0ull
#define OFF_HFRAG   40960ull                  // 6 slots * 32768 f16 = 393216 B
#define OFF_EMB     434176ull                 // [4096][1024] f16
#define OFF_X0      8822784ull                // [4096][4096] f16
#define OFF_WIH0    42377216ull               // [4096][1024] f16
#define OFF_WP4     50765824ull               // 256 wg * 65536 f16
#define OFF_WP0     84320256ull               // 256 wg * 16384 f16
#define OFF_EMBW    92708864ull               // [32000][1024] f16
#define OFF_WIN     158244864ull              // [1024][1024] f16
#define OFF_WOUT    160342016ull              // [1024][2048] f16
#define OFF_ENC     164536320ull              // [64][32][1024] f16
#define OFF_H2ALL   168730624ull              // [4096][1024] f16
#define OFF_CONCAT  177119232ull              // [4096][2048] f16
#define OFF_TARGET  193896448ull              // [4096][1024] f16
#define OFF_HT      202285056ull              // [4096][1024] f16
#define WS_NEEDED   210673664ull

// ---------------- f32 -> f16 convert (vectorized, grid-stride) ----------------
__global__ __launch_bounds__(256) void k_conv(const float* __restrict__ s,
                                              _Float16* __restrict__ d, int n4) {
  int i = blockIdx.x * blockDim.x + threadIdx.x;
  int st = gridDim.x * blockDim.x;
  for (; i < n4; i += st) {
    float4 v = ((const float4*)s)[i];
    h16x4 o; o[0] = (_Float16)v.x; o[1] = (_Float16)v.y; o[2] = (_Float16)v.z; o[3] = (_Float16)v.w;
    ((h16x4*)d)[i] = o;
  }
}

// ---------------- embedding gather -> f16 ----------------
__global__ __launch_bounds__(256) void k_gather(const int* __restrict__ tok,
                                                const float* __restrict__ embW,
                                                _Float16* __restrict__ emb) {
  int row = blockIdx.x;                 // row = t*32+b
  int t = tok[row];
  float4 v = ((const float4*)(embW + (size_t)t * EE))[threadIdx.x];
  h16x4 o; o[0] = (_Float16)v.x; o[1] = (_Float16)v.y; o[2] = (_Float16)v.z; o[3] = (_Float16)v.w;
  ((h16x4*)(emb + (size_t)row * EE))[threadIdx.x] = o;
}

// ---------------- pack 4 LDS-resident matrices (Wih1,Whh1,Wih2,Whh2) ----------------
// wg w owns hidden units 4*wp..4*wp+3 with wp=(w&7)*32+(w>>3)  (XCD-local X0 lines)
// Wpack4[w][mat][jj][k_lds] = W[layer][row(wp,jj)][k_lds ^ ((jj&7)<<3)]  (XOR pre-swizzle)
__global__ __launch_bounds__(256) void k_packw4(const float* __restrict__ Wih,
                                                const float* __restrict__ Whh,
                                                _Float16* __restrict__ out) {
  int i = blockIdx.x * blockDim.x + threadIdx.x;
  int st = gridDim.x * blockDim.x;
  const int total = 256 * 65536;
  for (; i < total; i += st) {
    int w = i >> 16, rem = i & 65535;
    int wp = (w & 7) * 32 + (w >> 3);
    int mat = rem >> 14, jj = (rem >> 10) & 15, k = rem & 1023;
    int layer = 1 + (mat >> 1), isHH = mat & 1;
    int row = ((jj >> 2) << 10) + (wp << 2) + (jj & 3);
    int ks = k ^ ((jj & 7) << 3);
    const float* src = (isHH ? Whh : Wih) + (size_t)layer * G4 * 1024 + (size_t)row * 1024 + ks;
    out[i] = (_Float16)(*src);
  }
}

// ---------------- pack Whh0 fragment-linear: [w][ks 0..31][lane 0..63][e 0..7] ----------------
__global__ __launch_bounds__(256) void k_packw0(const float* __restrict__ Whh,
                                                _Float16* __restrict__ out) {
  int i = blockIdx.x * blockDim.x + threadIdx.x;
  int st = gridDim.x * blockDim.x;
  const int total = 256 * 16384;
  for (; i < total; i += st) {
    int w = i >> 14, rem = i & 16383;
    int wp = (w & 7) * 32 + (w >> 3);
    int ks = rem >> 9, lane = (rem >> 3) & 63, e = rem & 7;
    int jj = lane & 15, q = lane >> 4;
    int row = ((jj >> 2) << 10) + (wp << 2) + (jj & 3);
    int k = ks * 32 + q * 8 + e;
    out[i] = (_Float16)Whh[(size_t)row * 1024 + k];   // layer 0
  }
}

// ---------------- init: sync flags + initial h fragments ----------------
// parity init per layer: l0 -> slot[0][1], l1 -> slot[1][0], l2 -> slot[2][1]
__global__ __launch_bounds__(256) void k_init(const float* __restrict__ h0,
                                              _Float16* __restrict__ hfrag,
                                              unsigned* __restrict__ sync) {
  int i = blockIdx.x * blockDim.x + threadIdx.x;
  if (i < 64 + 8192) sync[i] = 0u;   // pad + arrive (strided)
  if (i >= 3 * BB * HH) return;
  int l = i >> 15, rem = i & 32767;
  int b = rem >> 10, n = rem & 1023;
  int parI = (l == 1) ? 0 : 1;
  int tbb = b >> 4, ks = n >> 5, q = (n >> 3) & 3, e = n & 7;
  int lane2 = (b & 15) | (q << 4);
  hfrag[(size_t)(l * 2 + parI) * 32768 + ((size_t)(tbb * 32 + ks) * 64 + lane2) * 8 + e] =
      (_Float16)h0[i];
}

// ---------------- generic 128x128 BT GEMM (A[M,K] f16, B[N,K] f16) ----------------
// staging via global_load_lds width=16; XCD-aware block swizzle (grid % 8 == 0)
// EPI: 1 = f16 ; 2 = f16(tanh)   (big GEMMs use k_gemm256)
template <int EPI>
__global__ __launch_bounds__(256) void k_gemm(const _Float16* __restrict__ A,
                                              const _Float16* __restrict__ B,
                                              void* __restrict__ C, int M, int N, int K,
                                              const float* __restrict__ bias1,
                                              const float* __restrict__ bias2) {
  __shared__ _Float16 As[2][128 * 32];
  __shared__ _Float16 Bs[2][128 * 32];
  const int ntn = N / 128;
  const int nwg = gridDim.x;
  const int bid = (blockIdx.x & 7) * (nwg >> 3) + (blockIdx.x >> 3);
  const int tm = bid / ntn, tn = bid % ntn;
  const int tid = threadIdx.x, lane = tid & 63;
  const int wv = tid >> 6, wr = wv >> 1, wc = wv & 1;
  f32x4 acc[4][4] = {};

  auto stage = [&](int buf, int k0) {
#pragma unroll
    for (int i = 0; i < 2; ++i) {
      int eo = (i * 256 + tid) * 8;
      int r = eo >> 5, c = eo & 31;
      __builtin_amdgcn_global_load_lds(AS_G(A + (size_t)(tm * 128 + r) * K + k0 + c),
                                       AS_L(&As[buf][eo]), 16, 0, 0);
      __builtin_amdgcn_global_load_lds(AS_G(B + (size_t)(tn * 128 + r) * K + k0 + c),
                                       AS_L(&Bs[buf][eo]), 16, 0, 0);
    }
  };
  stage(0, 0);
  __syncthreads();
  const int nk = K / 32;
  for (int kt = 0; kt < nk; ++kt) {
    if (kt + 1 < nk) stage((kt + 1) & 1, (kt + 1) * 32);
    const int buf = kt & 1;
    h16x8 af[4], bfr[4];
#pragma unroll
    for (int mi = 0; mi < 4; ++mi)
      af[mi] = *(const h16x8*)&As[buf][(wr * 64 + mi * 16 + (lane & 15)) * 32 + (lane >> 4) * 8];
#pragma unroll
    for (int ni = 0; ni < 4; ++ni)
      bfr[ni] = *(const h16x8*)&Bs[buf][(wc * 64 + ni * 16 + (lane & 15)) * 32 + (lane >> 4) * 8];
#pragma unroll
    for (int mi = 0; mi < 4; ++mi)
#pragma unroll
      for (int ni = 0; ni < 4; ++ni)
        acc[mi][ni] = __builtin_amdgcn_mfma_f32_16x16x32_f16(af[mi], bfr[ni], acc[mi][ni], 0, 0, 0);
    __syncthreads();
  }
  const int rbase = tm * 128 + wr * 64;
  const int cbase = tn * 128 + wc * 64;
#pragma unroll
  for (int mi = 0; mi < 4; ++mi) {
#pragma unroll
    for (int ni = 0; ni < 4; ++ni) {
#pragma unroll
      for (int r = 0; r < 4; ++r) {
        int mm = rbase + mi * 16 + (lane >> 4) * 4 + r;
        int nn = cbase + ni * 16 + (lane & 15);
        float v = acc[mi][ni][r];
        if (EPI == 1) {
          ((_Float16*)C)[(size_t)mm * N + nn] = (_Float16)v;
        } else {
          ((_Float16*)C)[(size_t)mm * N + nn] = (_Float16)tanhf(v);
        }
      }
    }
  }
}

// ---------------- 256x256 BT GEMM, 3-slot LDS ring + counted vmcnt (T4) ----------------
// EPI: 0 = f32 + bias1 ; 1 = f16 + bias1 + bias2
template <int EPI>
__global__ __launch_bounds__(512, 2) void k_gemm256(const _Float16* __restrict__ A,
                                                    const _Float16* __restrict__ B,
                                                    void* __restrict__ C, int M, int N, int K,
                                                    const float* __restrict__ bias1,
                                                    const float* __restrict__ bias2) {
  extern __shared__ char glds[];
  _Float16* Asl = (_Float16*)glds;                     // [3][256*32]
  _Float16* Bsl = (_Float16*)(glds + 3 * 8192 * 2);    // [3][256*32]
  const int ntn = N / 256;
  const int nwg = gridDim.x;
  const int bid = (blockIdx.x & 7) * (nwg >> 3) + (blockIdx.x >> 3);
  const int tm = bid / ntn, tn = bid % ntn;
  const int tid = threadIdx.x, lane = tid & 63;
  const int wid = tid >> 6, wm = wid >> 2, wn = wid & 3;
  const int fr = lane & 15, fc = lane >> 4;
  const int srow0 = tid >> 2, sg = tid & 3;    // staging: row within 128-half, granule

  f32x4 acc[8][4] = {};
  const int nt = K / 32;

  auto stage = [&](int t) {
    const int slot = t % 3;
    const size_t kof = (size_t)t * 32 + sg * 8;
#pragma unroll
    for (int r = 0; r < 2; ++r) {
      int row = r * 128 + srow0;
      __builtin_amdgcn_global_load_lds(AS_G(A + (size_t)(tm * 256 + row) * K + kof),
                                       AS_L(&Asl[slot * 8192 + row * 32 + sg * 8]), 16, 0, 0);
    }
#pragma unroll
    for (int r = 0; r < 2; ++r) {
      int row = r * 128 + srow0;
      __builtin_amdgcn_global_load_lds(AS_G(B + (size_t)(tn * 256 + row) * K + kof),
                                       AS_L(&Bsl[slot * 8192 + row * 32 + sg * 8]), 16, 0, 0);
    }
  };

  stage(0);
  stage(1);
  asm volatile("s_waitcnt vmcnt(4)" ::: "memory");   // tile 0 landed (mine)
  asm volatile("s_barrier" ::: "memory");            // tile 0 landed (all waves)

  for (int t = 0; t < nt; ++t) {
    if (t + 2 < nt) {
      stage(t + 2);
      asm volatile("s_waitcnt vmcnt(4)" ::: "memory");   // tile t+1 landed; t+2 in flight
    } else {
      asm volatile("s_waitcnt vmcnt(0)" ::: "memory");   // tail drain
    }
    asm volatile("s_barrier" ::: "memory");              // globalize tile t+1 / protect ring
    const int slot = t % 3;
    const _Float16* as = &Asl[slot * 8192];
    const _Float16* bs = &Bsl[slot * 8192];
    h16x8 af[8], bf[4];
#pragma unroll
    for (int mi = 0; mi < 8; ++mi)
      af[mi] = *(const h16x8*)&as[(wm * 128 + mi * 16 + fr) * 32 + fc * 8];
#pragma unroll
    for (int ni = 0; ni < 4; ++ni)
      bf[ni] = *(const h16x8*)&bs[(wn * 64 + ni * 16 + fr) * 32 + fc * 8];
    __builtin_amdgcn_s_setprio(1);
#pragma unroll
    for (int mi = 0; mi < 8; ++mi)
#pragma unroll
      for (int ni = 0; ni < 4; ++ni)
        acc[mi][ni] = __builtin_amdgcn_mfma_f32_16x16x32_f16(af[mi], bf[ni], acc[mi][ni], 0, 0, 0);
    __builtin_amdgcn_s_setprio(0);
    asm volatile("s_barrier" ::: "memory");   // my reads of slot done before others restage it
  }

  const int rbase = tm * 256 + wm * 128;
  const int cbase = tn * 256 + wn * 64;
#pragma unroll
  for (int mi = 0; mi < 8; ++mi) {
#pragma unroll
    for (int ni = 0; ni < 4; ++ni) {
#pragma unroll
      for (int r = 0; r < 4; ++r) {
        int mm = rbase + mi * 16 + fc * 4 + r;
        int nn = cbase + ni * 16 + fr;
        float v = acc[mi][ni][r];
        if (EPI == 0) {
          ((float*)C)[(size_t)mm * N + nn] = v + bias1[nn];
        } else {
          ((_Float16*)C)[(size_t)mm * N + nn] = (_Float16)(v + bias1[nn] + bias2[nn]);
        }
      }
    }
  }
}

// ---------------- persistent pipelined LSTM recurrence ----------------
// 256 wgs x 512 thr. wg w owns hidden units 4*wp..4*wp+3, wp=(w&7)*32+(w>>3)
// (XCD x hosts wgs w%8==x -> owns contiguous units [128x,128x+128): X0 64B
// lines are consumed within ONE XCD - no cross-XCD line overfetch).
// Exchange: h via sc1 8B stores; h READS via sc0+sc1 16B loads (LLC-direct,
// no L2 allocation) => NO acquire fence / L2 invalidation per tick; X0,
// biases, weights stay warm in L2. Flag protocol = R5-proven strided+sleep.
__global__ __launch_bounds__(512) void k_recur(const _Float16* __restrict__ Wp4,
                                               const _Float16* __restrict__ Wp0,
                                               const _Float16* __restrict__ X0bf,
                                               _Float16* __restrict__ hfrag,
                                               _Float16* __restrict__ h2all,
                                               _Float16* __restrict__ concat,
                                               const float* __restrict__ bih,
                                               const float* __restrict__ bhh,
                                               const float* __restrict__ c0p,
                                               unsigned* __restrict__ sync) {
  extern __shared__ char lds[];
  _Float16* ldsW = (_Float16*)lds;                 // 65536 f16
  float* redbuf = (float*)(lds + 131072);          // [3][3][2][256]
  _Float16* hstage = (_Float16*)(lds + 131072);    // [3][128] (reused after redbuf)
  float* gbuf = (float*)(lds + 149504);            // [3][32][16]
  unsigned* arrive = sync + 64;                    // strided: arrive[w*32]

  const int w = blockIdx.x;
  const int wp = (w & 7) * 32 + (w >> 3);          // XCD-local unit-block remap
  const int tid = threadIdx.x, lane = tid & 63, wv = tid >> 6;
  const int tb = wv & 1, kq = wv >> 1;
  const int row = (lane >> 4) * 4, col = lane & 15;

  // preload LDS weights (linear copy; swizzle pre-applied by k_packw4)
  for (int i = 0; i < 16; ++i) {
    int eo = (i * 512 + tid) * 8;
    *(h16x8*)&ldsW[eo] = *(const h16x8*)(Wp4 + (size_t)w * 65536 + eo);
  }
  // Whh0 fragments in registers
  h16x8 w0reg[8];
#pragma unroll
  for (int i = 0; i < 8; ++i)
    w0reg[i] = *(const h16x8*)(Wp0 + (size_t)w * 16384 + ((size_t)(kq * 8 + i) * 64 + lane) * 8);

  // per-thread epilogue state (threads 0..127 own (b, ni))
  const int eb = tid >> 2, eni = tid & 3, en = wp * 4 + eni;
  float c0r = 0.f, c1r = 0.f, c2r = 0.f;
  float b1r[4] = {0, 0, 0, 0}, b2r[4] = {0, 0, 0, 0};
  if (tid < 128) {
    c0r = c0p[0 * BB * HH + eb * HH + en];
    c1r = c0p[1 * BB * HH + eb * HH + en];
    c2r = c0p[2 * BB * HH + eb * HH + en];
#pragma unroll
    for (int g = 0; g < 4; ++g) {
      b1r[g] = bih[1 * G4 + g * 1024 + en] + bhh[1 * G4 + g * 1024 + en];
      b2r[g] = bih[2 * G4 + g * 1024 + en] + bhh[2 * G4 + g * 1024 + en];
    }
  }
  // pack-phase constants: thread (pk_l, pk_r) stores layer pk_l, batch row pk_r
  const int pk_l = tid >> 5, pk_r = tid & 31;
  const size_t pk_idx = ((size_t)(((pk_r >> 4) * 32 + (wp >> 3)) * 64 + (pk_r & 15) +
                                  (((wp >> 1) & 3) << 4))) * 8 + 4 * (wp & 1);
  __syncthreads();

  for (int tau = 0; tau < 130; ++tau) {
    const int p = tau & 1;
    const _Float16* h0r = hfrag + (size_t)(0 + (1 - p)) * 32768;
    const _Float16* h1r = hfrag + (size_t)(2 + (1 - p)) * 32768;
    const _Float16* h2r = hfrag + (size_t)(4 + (1 - p)) * 32768;

    // A fragments: LLC-direct loads (batched; drained once below)
    f32x4 a0f[8], a1f[8], a2f[8];
#pragma unroll
    for (int i = 0; i < 8; ++i) {
      int ks = kq * 8 + i;
      size_t off = ((size_t)(tb * 32 + ks) * 64 + lane) * 8;
      a0f[i] = llc_load16(h0r + off);
      a1f[i] = llc_load16(h1r + off);
      a2f[i] = llc_load16(h2r + off);
    }
    // X0 gate loads: normal cached (L2 warm - no per-tick invalidation anymore)
    float xg0 = 0.f, xg1 = 0.f, xg2 = 0.f, xg3 = 0.f;
    if (tid < 128 && tau < 128) {
      size_t xb = ((size_t)(tau * BB + eb)) * G4 + en;
      xg0 = (float)X0bf[xb];        xg1 = (float)X0bf[xb + 1024];
      xg2 = (float)X0bf[xb + 2048]; xg3 = (float)X0bf[xb + 3072];
    }
    asm volatile("s_waitcnt vmcnt(0)" ::: "memory");   // all h loads landed
    __builtin_amdgcn_sched_barrier(0);                 // rule #18: pin MFMA after wait

    f32x4 acc0 = {}, acc1 = {}, acc2 = {};
#pragma unroll
    for (int i = 0; i < 8; ++i) {
      int ks = kq * 8 + i;
      int jj = lane & 15, q = lane >> 4;
      int kk = (ks * 32 + q * 8) ^ ((jj & 7) << 3);
      const h16x8 bw1i = *(const h16x8*)&ldsW[0 * 16384 + jj * 1024 + kk];
      const h16x8 bw1h = *(const h16x8*)&ldsW[1 * 16384 + jj * 1024 + kk];
      const h16x8 bw2i = *(const h16x8*)&ldsW[2 * 16384 + jj * 1024 + kk];
      const h16x8 bw2h = *(const h16x8*)&ldsW[3 * 16384 + jj * 1024 + kk];
      acc0 = __builtin_amdgcn_mfma_f32_16x16x32_f16(*(h16x8*)&a0f[i], w0reg[i], acc0, 0, 0, 0);
      acc1 = __builtin_amdgcn_mfma_f32_16x16x32_f16(*(h16x8*)&a0f[i], bw1i, acc1, 0, 0, 0);
      acc1 = __builtin_amdgcn_mfma_f32_16x16x32_f16(*(h16x8*)&a1f[i], bw1h, acc1, 0, 0, 0);
      acc2 = __builtin_amdgcn_mfma_f32_16x16x32_f16(*(h16x8*)&a1f[i], bw2i, acc2, 0, 0, 0);
      acc2 = __builtin_amdgcn_mfma_f32_16x16x32_f16(*(h16x8*)&a2f[i], bw2h, acc2, 0, 0, 0);
    }
    // cross-wave K reduction
    if (kq >= 1) {
      int s = kq - 1;
#pragma unroll
      for (int r = 0; r < 4; ++r) {
        redbuf[((0 * 3 + s) * 2 + tb) * 256 + (row + r) * 16 + col] = acc0[r];
        redbuf[((1 * 3 + s) * 2 + tb) * 256 + (row + r) * 16 + col] = acc1[r];
        redbuf[((2 * 3 + s) * 2 + tb) * 256 + (row + r) * 16 + col] = acc2[r];
      }
    }
    __syncthreads();
    if (kq == 0) {
#pragma unroll
      for (int r = 0; r < 4; ++r) {
        float v0 = acc0[r], v1 = acc1[r], v2 = acc2[r];
#pragma unroll
        for (int s = 0; s < 3; ++s) {
          v0 += redbuf[((0 * 3 + s) * 2 + tb) * 256 + (row + r) * 16 + col];
          v1 += redbuf[((1 * 3 + s) * 2 + tb) * 256 + (row + r) * 16 + col];
          v2 += redbuf[((2 * 3 + s) * 2 + tb) * 256 + (row + r) * 16 + col];
        }
        gbuf[(0 * 32 + tb * 16 + row + r) * 16 + col] = v0;
        gbuf[(1 * 32 + tb * 16 + row + r) * 16 + col] = v1;
        gbuf[(2 * 32 + tb * 16 + row + r) * 16 + col] = v2;
      }
    }
    __syncthreads();
    // elementwise LSTM epilogue -> hstage (LDS) + h2all/concat (regular stores)
    if (tid < 128) {
      if (tau < 128) {  // layer 0: X0 already holds x@Wih0^T + b_ih0 + b_hh0
        float gi = gbuf[(0 * 32 + eb) * 16 + eni] + xg0;
        float gf = gbuf[(0 * 32 + eb) * 16 + 4 + eni] + xg1;
        float gg = gbuf[(0 * 32 + eb) * 16 + 8 + eni] + xg2;
        float go = gbuf[(0 * 32 + eb) * 16 + 12 + eni] + xg3;
        c0r = sigmf(gf) * c0r + sigmf(gi) * tanhf(gg);
        hstage[0 * 128 + tid] = (_Float16)(sigmf(go) * tanhf(c0r));
      }
      if (tau >= 1 && tau < 129) {  // layer 1
        float gi = gbuf[(1 * 32 + eb) * 16 + eni] + b1r[0];
        float gf = gbuf[(1 * 32 + eb) * 16 + 4 + eni] + b1r[1];
        float gg = gbuf[(1 * 32 + eb) * 16 + 8 + eni] + b1r[2];
        float go = gbuf[(1 * 32 + eb) * 16 + 12 + eni] + b1r[3];
        c1r = sigmf(gf) * c1r + sigmf(gi) * tanhf(gg);
        hstage[1 * 128 + tid] = (_Float16)(sigmf(go) * tanhf(c1r));
      }
      if (tau >= 2) {  // layer 2
        float gi = gbuf[(2 * 32 + eb) * 16 + eni] + b2r[0];
        float gf = gbuf[(2 * 32 + eb) * 16 + 4 + eni] + b2r[1];
        float gg = gbuf[(2 * 32 + eb) * 16 + 8 + eni] + b2r[2];
        float go = gbuf[(2 * 32 + eb) * 16 + 12 + eni] + b2r[3];
        c2r = sigmf(gf) * c2r + sigmf(gi) * tanhf(gg);
        float h = sigmf(go) * tanhf(c2r);
        _Float16 hb = (_Float16)h;
        hstage[2 * 128 + tid] = hb;
        int t2 = tau - 2;
        h2all[(size_t)(t2 * BB + eb) * HH + en] = hb;
        concat[(size_t)(t2 * BB + eb) * 2048 + 1024 + en] = hb;
      }
    }
    __syncthreads();   // hstage visible in LDS
    // pack phase (R5 protocol): 96 threads emit one 8B agent-scope (sc1) store
    {
      bool act = (tid < 96) &&
                 ((pk_l == 0) ? (tau < 128)
                  : (pk_l == 1) ? (tau >= 1 && tau < 129) : (tau >= 2));
      if (act) {
        unsigned long long v = *(const unsigned long long*)&hstage[pk_l * 128 + pk_r * 4];
        __hip_atomic_store(
            (unsigned long long*)(hfrag + (size_t)(pk_l * 2 + p) * 32768 + pk_idx), v,
            __ATOMIC_RELAXED, __HIP_MEMORY_SCOPE_AGENT);
      }
      asm volatile("s_waitcnt vmcnt(0)" ::: "memory");   // own sc1 stores at LLC
    }
    __syncthreads();   // all pack stores complete before flag
    if (tid == 0)
      __hip_atomic_store(&arrive[w * 32], (unsigned)(tau + 1), __ATOMIC_RELAXED,
                         __HIP_MEMORY_SCOPE_AGENT);
    if (tau < 129) {   // last tick: no one consumes, skip the wait
      if (tid < 64) {
        for (;;) {
          bool ok = true;
#pragma unroll
          for (int j = 0; j < 4; ++j) {
            unsigned v = __hip_atomic_load(&arrive[(tid * 4 + j) * 32], __ATOMIC_RELAXED,
                                           __HIP_MEMORY_SCOPE_AGENT);
            ok &= (v >= (unsigned)(tau + 1));
          }
          if (__all(ok)) break;
          __builtin_amdgcn_s_sleep(1);
        }
        // no cache maintenance: h reads bypass L1/L2 (sc0 sc1); other data immutable
        asm volatile("" ::: "memory");
      }
      __syncthreads();
    }
  }
}

// ---------------- fused scores+softmax+weighted-context per (t,b) ----------------
__global__ __launch_bounds__(256) void k_attn(const _Float16* __restrict__ target,
                                              const _Float16* __restrict__ encb,
                                              _Float16* __restrict__ concat) {
  __shared__ float sc[64];
  __shared__ float att[64];
  int m = blockIdx.x, b = m & 31;
  int tid = threadIdx.x, lane = tid & 63, wv = tid >> 6;
  const h16x8* tp = (const h16x8*)(target + (size_t)m * EE + lane * 16);
  h16x8 tg0 = tp[0], tg1 = tp[1];
  for (int si = 0; si < 16; ++si) {
    int s = wv * 16 + si;
    const h16x8* ep = (const h16x8*)(encb + ((size_t)s * BB + b) * EE + lane * 16);
    h16x8 e0 = ep[0], e1 = ep[1];
    float a = 0.f;
#pragma unroll
    for (int j = 0; j < 8; ++j) a += (float)e0[j] * (float)tg0[j];
#pragma unroll
    for (int j = 0; j < 8; ++j) a += (float)e1[j] * (float)tg1[j];
#pragma unroll
    for (int off = 32; off >= 1; off >>= 1) a += __shfl_xor(a, off);
    if (lane == 0) sc[s] = a;
  }
  __syncthreads();
  if (wv == 0) {
    float v = sc[lane], mx = v;
#pragma unroll
    for (int off = 32; off >= 1; off >>= 1) mx = fmaxf(mx, __shfl_xor(mx, off));
    float e = expf(v - mx), sm = e;
#pragma unroll
    for (int off = 32; off >= 1; off >>= 1) sm += __shfl_xor(sm, off);
    att[lane] = e / sm;
  }
  __syncthreads();
  int e4 = tid * 4;
  float a0 = 0, a1 = 0, a2 = 0, a3 = 0;
  for (int s = 0; s < 64; ++s) {
    float wgt = att[s];
    h16x4 ev = *(const h16x4*)(encb + ((size_t)s * BB + b) * EE + e4);
    a0 += wgt * (float)ev[0]; a1 += wgt * (float)ev[1];
    a2 += wgt * (float)ev[2]; a3 += wgt * (float)ev[3];
  }
  h16x4 o; o[0] = (_Float16)a0; o[1] = (_Float16)a1; o[2] = (_Float16)a2; o[3] = (_Float16)a3;
  *(h16x4*)(concat + (size_t)m * 2048 + e4) = o;
}

// ---------------- host ----------------
extern "C" void kernel_launch(void* const* d_in, const int* in_sizes, int n_in,
                              void* d_out, int out_size, void* d_ws, size_t ws_size,
                              hipStream_t stream) {
  const int* tokens = (const int*)d_in[0];
  const float* embW = (const float*)d_in[1];
  const float* Wih = (const float*)d_in[2];
  const float* Whh = (const float*)d_in[3];
  const float* bih = (const float*)d_in[4];
  const float* bhh = (const float*)d_in[5];
  const float* Win = (const float*)d_in[6];
  const float* Wout = (const float*)d_in[7];
  const float* finalb = (const float*)d_in[8];
  const float* enc = (const float*)d_in[9];
  const float* h0 = (const float*)d_in[10];
  const float* c0 = (const float*)d_in[11];
  (void)in_sizes; (void)n_in; (void)out_size;
  if (ws_size < WS_NEEDED) return;

  char* ws = (char*)d_ws;
  unsigned* sync = (unsigned*)(ws + OFF_SYNC);
  _Float16* hfrag = (_Float16*)(ws + OFF_HFRAG);
  _Float16* emb = (_Float16*)(ws + OFF_EMB);
  _Float16* X0bf = (_Float16*)(ws + OFF_X0);
  _Float16* Wih0b = (_Float16*)(ws + OFF_WIH0);
  _Float16* Wp4 = (_Float16*)(ws + OFF_WP4);
  _Float16* Wp0 = (_Float16*)(ws + OFF_WP0);
  _Float16* embWb = (_Float16*)(ws + OFF_EMBW);
  _Float16* Winb = (_Float16*)(ws + OFF_WIN);
  _Float16* Woutb = (_Float16*)(ws + OFF_WOUT);
  _Float16* encb = (_Float16*)(ws + OFF_ENC);
  _Float16* h2all = (_Float16*)(ws + OFF_H2ALL);
  _Float16* concat = (_Float16*)(ws + OFF_CONCAT);
  _Float16* target = (_Float16*)(ws + OFF_TARGET);
  _Float16* ht = (_Float16*)(ws + OFF_HT);

  const unsigned LDSB = 155648;   // k_recur: 128KB weights + 18KB redbuf + 6KB gbuf
  const unsigned LDSG = 98304;    // k_gemm256: 3 slots x (A 16KB + B 16KB)
  static int lds_set = 0;
  if (!lds_set) {
    hipFuncSetAttribute((const void*)k_recur, hipFuncAttributeMaxDynamicSharedMemorySize,
                        (int)LDSB);
    hipFuncSetAttribute((const void*)k_gemm256<0>, hipFuncAttributeMaxDynamicSharedMemorySize,
                        (int)LDSG);
    hipFuncSetAttribute((const void*)k_gemm256<1>, hipFuncAttributeMaxDynamicSharedMemorySize,
                        (int)LDSG);
    lds_set = 1;   // attributes are sticky on the functions
  }

  // prep: converts / packs / init
  k_conv<<<4096, 256, 0, stream>>>(embW, embWb, VV * EE / 4);
  k_conv<<<1024, 256, 0, stream>>>(Wih, Wih0b, G4 * EE / 4);       // layer-0 W_ih
  k_conv<<<512, 256, 0, stream>>>(Win, Winb, EE * EE / 4);
  k_conv<<<512, 256, 0, stream>>>(Wout, Woutb, EE * 2048 / 4);
  k_conv<<<512, 256, 0, stream>>>(enc, encb, 64 * BB * EE / 4);
  k_gather<<<NROWS, 256, 0, stream>>>(tokens, embW, emb);
  k_packw4<<<8192, 256, 0, stream>>>(Wih, Whh, Wp4);
  k_packw0<<<4096, 256, 0, stream>>>(Whh, Wp0);
  k_init<<<384, 256, 0, stream>>>(h0, hfrag, sync);

  // X0 = emb @ Wih0^T + b_ih0 + b_hh0   -> f16 [4096,4096]  (256-tile counted-vmcnt GEMM)
  k_gemm256<1><<<16 * 16, 512, LDSG, stream>>>(emb, Wih0b, X0bf, NROWS, G4, EE, bih, bhh);

  // recurrence: REGULAR launch (graph-capturable); co-residency structural
  k_recur<<<256, 512, LDSB, stream>>>(Wp4, Wp0, X0bf, hfrag, h2all, concat,
                                      bih, bhh, c0, sync);

  // attention chain
  k_gemm<1><<<32 * 8, 256, 0, stream>>>(h2all, Winb, target, NROWS, EE, EE, nullptr, nullptr);
  k_attn<<<NROWS, 256, 0, stream>>>(target, encb, concat);
  k_gemm<2><<<32 * 8, 256, 0, stream>>>(concat, Woutb, ht, NROWS, EE, 2048, nullptr, nullptr);

  // logits = ht @ embW^T + final_b  -> f32 d_out  (256-tile counted-vmcnt GEMM)
  k_gemm256<0><<<16 * 125, 512, LDSG, stream>>>(ht, embWb, d_out, NROWS, VV, EE, finalb, nullptr);
}

// Round 11
// 1424.855 us; speedup vs baseline: 1.4056x; 1.0197x over previous
//
#include <hip/hip_runtime.h>
#include <cstdint>
#include <cstddef>

#define SEQ   128
#define BB    32
#define EE    1024
#define HH    1024
#define G4    4096
#define VV    32000
#define NROWS 4096   // SEQ*BB

typedef _Float16 h16x8 __attribute__((ext_vector_type(8)));
typedef _Float16 h16x4 __attribute__((ext_vector_type(4)));
typedef float f32x4  __attribute__((ext_vector_type(4)));

#define AS_G(p) ((const __attribute__((address_space(1))) void*)(p))
#define AS_L(p) ((__attribute__((address_space(3))) void*)(p))

__device__ __forceinline__ float sigmf(float x) { return 1.0f / (1.0f + expf(-x)); }

// ---------------- ws layout (bytes) ----------------
// hfrag = monotonic slot ring: slot s holds [3 layers][32768 f16] (196608 B).
// slots 0..2: dedicated region (written by k_init BEFORE the big GEMMs).
// slots 3..129: overlay EMB+WIH0+TARGET (dead during the recurrence:
//   EMB/WIH0 consumed by X0-GEMM before k_recur; TARGET written after).
#define OFF_SYNC    0ull                      // pad[64] + arrive[256] strided 128B
#define OFF_HFRAG0  40960ull                  // 3 slots  * 196608 = 589824
#define OFF_EMB     630784ull                 // [4096][1024] f16   (8388608)
#define OFF_WIH0    9019392ull                // [4096][1024] f16   (8388608)
#define OFF_TARGET  17408000ull               // [4096][1024] f16   (8388608)
#define OFF_HT      25796608ull               // [4096][1024] f16   (8388608)
#define OFF_HFRAGH  630784ull                 // 127 slots * 196608 = 24969216 (overlay)
#define OFF_X0      34185216ull               // [4096][4096] f16   (33554432)
#define OFF_WP4     67739648ull               // 256 wg * 65536 f16 (33554432)
#define OFF_WP0     101294080ull              // 256 wg * 16384 f16 (8388608)
#define OFF_EMBW    109682688ull              // [32000][1024] f16  (65536000)
#define OFF_WIN     175218688ull              // [1024][1024] f16   (2097152)
#define OFF_WOUT    177315840ull              // [1024][2048] f16   (4194304)
#define OFF_ENC     181510144ull              // [64][32][1024] f16 (4194304)
#define OFF_H2ALL   185704448ull              // [4096][1024] f16   (8388608)
#define OFF_CONCAT  194093056ull              // [4096][2048] f16   (16777216)
#define WS_NEEDED   210870272ull

// ---------------- f32 -> f16 convert (vectorized, grid-stride) ----------------
__global__ __launch_bounds__(256) void k_conv(const float* __restrict__ s,
                                              _Float16* __restrict__ d, int n4) {
  int i = blockIdx.x * blockDim.x + threadIdx.x;
  int st = gridDim.x * blockDim.x;
  for (; i < n4; i += st) {
    float4 v = ((const float4*)s)[i];
    h16x4 o; o[0] = (_Float16)v.x; o[1] = (_Float16)v.y; o[2] = (_Float16)v.z; o[3] = (_Float16)v.w;
    ((h16x4*)d)[i] = o;
  }
}

// ---------------- embedding gather -> f16 ----------------
__global__ __launch_bounds__(256) void k_gather(const int* __restrict__ tok,
                                                const float* __restrict__ embW,
                                                _Float16* __restrict__ emb) {
  int row = blockIdx.x;                 // row = t*32+b
  int t = tok[row];
  float4 v = ((const float4*)(embW + (size_t)t * EE))[threadIdx.x];
  h16x4 o; o[0] = (_Float16)v.x; o[1] = (_Float16)v.y; o[2] = (_Float16)v.z; o[3] = (_Float16)v.w;
  ((h16x4*)(emb + (size_t)row * EE))[threadIdx.x] = o;
}

// ---------------- pack 4 LDS-resident matrices (Wih1,Whh1,Wih2,Whh2) ----------------
// wg w owns hidden units 4*wp..4*wp+3 with wp=(w&7)*32+(w>>3)  (XCD-local X0 lines)
// Wpack4[w][mat][jj][k_lds] = W[layer][row(wp,jj)][k_lds ^ ((jj&7)<<3)]  (XOR pre-swizzle)
__global__ __launch_bounds__(256) void k_packw4(const float* __restrict__ Wih,
                                                const float* __restrict__ Whh,
                                                _Float16* __restrict__ out) {
  int i = blockIdx.x * blockDim.x + threadIdx.x;
  int st = gridDim.x * blockDim.x;
  const int total = 256 * 65536;
  for (; i < total; i += st) {
    int w = i >> 16, rem = i & 65535;
    int wp = (w & 7) * 32 + (w >> 3);
    int mat = rem >> 14, jj = (rem >> 10) & 15, k = rem & 1023;
    int layer = 1 + (mat >> 1), isHH = mat & 1;
    int row = ((jj >> 2) << 10) + (wp << 2) + (jj & 3);
    int ks = k ^ ((jj & 7) << 3);
    const float* src = (isHH ? Whh : Wih) + (size_t)layer * G4 * 1024 + (size_t)row * 1024 + ks;
    out[i] = (_Float16)(*src);
  }
}

// ---------------- pack Whh0 fragment-linear: [w][ks 0..31][lane 0..63][e 0..7] ----------------
__global__ __launch_bounds__(256) void k_packw0(const float* __restrict__ Whh,
                                                _Float16* __restrict__ out) {
  int i = blockIdx.x * blockDim.x + threadIdx.x;
  int st = gridDim.x * blockDim.x;
  const int total = 256 * 16384;
  for (; i < total; i += st) {
    int w = i >> 14, rem = i & 16383;
    int wp = (w & 7) * 32 + (w >> 3);
    int ks = rem >> 9, lane = (rem >> 3) & 63, e = rem & 7;
    int jj = lane & 15, q = lane >> 4;
    int row = ((jj >> 2) << 10) + (wp << 2) + (jj & 3);
    int k = ks * 32 + q * 8 + e;
    out[i] = (_Float16)Whh[(size_t)row * 1024 + k];   // layer 0
  }
}

// ---------------- init: sync flags + initial h into slots 0..2 ----------------
// h0_init -> slot0.l0 (read at tau=0); h1_init -> slot1.l1 (read at tau=1);
// h2_init -> slot2.l2 (read at tau=2). slot stride 98304 f16; layer stride 32768.
__global__ __launch_bounds__(256) void k_init(const float* __restrict__ h0,
                                              _Float16* __restrict__ hfrag0,
                                              unsigned* __restrict__ sync) {
  int i = blockIdx.x * blockDim.x + threadIdx.x;
  if (i < 64 + 8192) sync[i] = 0u;   // pad + arrive (strided)
  if (i >= 3 * BB * HH) return;
  int l = i >> 15, rem = i & 32767;
  int b = rem >> 10, n = rem & 1023;
  int tbb = b >> 4, ks = n >> 5, q = (n >> 3) & 3, e = n & 7;
  int lane2 = (b & 15) | (q << 4);
  hfrag0[(size_t)l * 131072 + ((size_t)(tbb * 32 + ks) * 64 + lane2) * 8 + e] =
      (_Float16)h0[i];
}

// ---------------- generic 128x128 BT GEMM (A[M,K] f16, B[N,K] f16) ----------------
// staging via global_load_lds width=16; XCD-aware block swizzle (grid % 8 == 0)
// EPI: 1 = f16 ; 2 = f16(tanh)   (big GEMMs use k_gemm256)
template <int EPI>
__global__ __launch_bounds__(256) void k_gemm(const _Float16* __restrict__ A,
                                              const _Float16* __restrict__ B,
                                              void* __restrict__ C, int M, int N, int K,
                                              const float* __restrict__ bias1,
                                              const float* __restrict__ bias2) {
  __shared__ _Float16 As[2][128 * 32];
  __shared__ _Float16 Bs[2][128 * 32];
  const int ntn = N / 128;
  const int nwg = gridDim.x;
  const int bid = (blockIdx.x & 7) * (nwg >> 3) + (blockIdx.x >> 3);
  const int tm = bid / ntn, tn = bid % ntn;
  const int tid = threadIdx.x, lane = tid & 63;
  const int wv = tid >> 6, wr = wv >> 1, wc = wv & 1;
  f32x4 acc[4][4] = {};

  auto stage = [&](int buf, int k0) {
#pragma unroll
    for (int i = 0; i < 2; ++i) {
      int eo = (i * 256 + tid) * 8;
      int r = eo >> 5, c = eo & 31;
      __builtin_amdgcn_global_load_lds(AS_G(A + (size_t)(tm * 128 + r) * K + k0 + c),
                                       AS_L(&As[buf][eo]), 16, 0, 0);
      __builtin_amdgcn_global_load_lds(AS_G(B + (size_t)(tn * 128 + r) * K + k0 + c),
                                       AS_L(&Bs[buf][eo]), 16, 0, 0);
    }
  };
  stage(0, 0);
  __syncthreads();
  const int nk = K / 32;
  for (int kt = 0; kt < nk; ++kt) {
    if (kt + 1 < nk) stage((kt + 1) & 1, (kt + 1) * 32);
    const int buf = kt & 1;
    h16x8 af[4], bfr[4];
#pragma unroll
    for (int mi = 0; mi < 4; ++mi)
      af[mi] = *(const h16x8*)&As[buf][(wr * 64 + mi * 16 + (lane & 15)) * 32 + (lane >> 4) * 8];
#pragma unroll
    for (int ni = 0; ni < 4; ++ni)
      bfr[ni] = *(const h16x8*)&Bs[buf][(wc * 64 + ni * 16 + (lane & 15)) * 32 + (lane >> 4) * 8];
#pragma unroll
    for (int mi = 0; mi < 4; ++mi)
#pragma unroll
      for (int ni = 0; ni < 4; ++ni)
        acc[mi][ni] = __builtin_amdgcn_mfma_f32_16x16x32_f16(af[mi], bfr[ni], acc[mi][ni], 0, 0, 0);
    __syncthreads();
  }
  const int rbase = tm * 128 + wr * 64;
  const int cbase = tn * 128 + wc * 64;
#pragma unroll
  for (int mi = 0; mi < 4; ++mi) {
#pragma unroll
    for (int ni = 0; ni < 4; ++ni) {
#pragma unroll
      for (int r = 0; r < 4; ++r) {
        int mm = rbase + mi * 16 + (lane >> 4) * 4 + r;
        int nn = cbase + ni * 16 + (lane & 15);
        float v = acc[mi][ni][r];
        if (EPI == 1) {
          ((_Float16*)C)[(size_t)mm * N + nn] = (_Float16)v;
        } else {
          ((_Float16*)C)[(size_t)mm * N + nn] = (_Float16)tanhf(v);
        }
      }
    }
  }
}

// ---------------- 256x256 BT GEMM, 3-slot LDS ring + counted vmcnt (T4) ----------------
// EPI: 0 = f32 + bias1 ; 1 = f16 + bias1 + bias2
template <int EPI>
__global__ __launch_bounds__(512, 2) void k_gemm256(const _Float16* __restrict__ A,
                                                    const _Float16* __restrict__ B,
                                                    void* __restrict__ C, int M, int N, int K,
                                                    const float* __restrict__ bias1,
                                                    const float* __restrict__ bias2) {
  extern __shared__ char glds[];
  _Float16* Asl = (_Float16*)glds;                     // [3][256*32]
  _Float16* Bsl = (_Float16*)(glds + 3 * 8192 * 2);    // [3][256*32]
  const int ntn = N / 256;
  const int nwg = gridDim.x;
  const int bid = (blockIdx.x & 7) * (nwg >> 3) + (blockIdx.x >> 3);
  const int tm = bid / ntn, tn = bid % ntn;
  const int tid = threadIdx.x, lane = tid & 63;
  const int wid = tid >> 6, wm = wid >> 2, wn = wid & 3;
  const int fr = lane & 15, fc = lane >> 4;
  const int srow0 = tid >> 2, sg = tid & 3;    // staging: row within 128-half, granule

  f32x4 acc[8][4] = {};
  const int nt = K / 32;

  auto stage = [&](int t) {
    const int slot = t % 3;
    const size_t kof = (size_t)t * 32 + sg * 8;
#pragma unroll
    for (int r = 0; r < 2; ++r) {
      int row = r * 128 + srow0;
      __builtin_amdgcn_global_load_lds(AS_G(A + (size_t)(tm * 256 + row) * K + kof),
                                       AS_L(&Asl[slot * 8192 + row * 32 + sg * 8]), 16, 0, 0);
    }
#pragma unroll
    for (int r = 0; r < 2; ++r) {
      int row = r * 128 + srow0;
      __builtin_amdgcn_global_load_lds(AS_G(B + (size_t)(tn * 256 + row) * K + kof),
                                       AS_L(&Bsl[slot * 8192 + row * 32 + sg * 8]), 16, 0, 0);
    }
  };

  stage(0);
  stage(1);
  asm volatile("s_waitcnt vmcnt(4)" ::: "memory");   // tile 0 landed (mine)
  asm volatile("s_barrier" ::: "memory");            // tile 0 landed (all waves)

  for (int t = 0; t < nt; ++t) {
    if (t + 2 < nt) {
      stage(t + 2);
      asm volatile("s_waitcnt vmcnt(4)" ::: "memory");   // tile t+1 landed; t+2 in flight
    } else {
      asm volatile("s_waitcnt vmcnt(0)" ::: "memory");   // tail drain
    }
    asm volatile("s_barrier" ::: "memory");              // globalize tile t+1 / protect ring
    const int slot = t % 3;
    const _Float16* as = &Asl[slot * 8192];
    const _Float16* bs = &Bsl[slot * 8192];
    h16x8 af[8], bf[4];
#pragma unroll
    for (int mi = 0; mi < 8; ++mi)
      af[mi] = *(const h16x8*)&as[(wm * 128 + mi * 16 + fr) * 32 + fc * 8];
#pragma unroll
    for (int ni = 0; ni < 4; ++ni)
      bf[ni] = *(const h16x8*)&bs[(wn * 64 + ni * 16 + fr) * 32 + fc * 8];
    __builtin_amdgcn_s_setprio(1);
#pragma unroll
    for (int mi = 0; mi < 8; ++mi)
#pragma unroll
      for (int ni = 0; ni < 4; ++ni)
        acc[mi][ni] = __builtin_amdgcn_mfma_f32_16x16x32_f16(af[mi], bf[ni], acc[mi][ni], 0, 0, 0);
    __builtin_amdgcn_s_setprio(0);
    asm volatile("s_barrier" ::: "memory");   // my reads of slot done before others restage it
  }

  const int rbase = tm * 256 + wm * 128;
  const int cbase = tn * 256 + wn * 64;
#pragma unroll
  for (int mi = 0; mi < 8; ++mi) {
#pragma unroll
    for (int ni = 0; ni < 4; ++ni) {
#pragma unroll
      for (int r = 0; r < 4; ++r) {
        int mm = rbase + mi * 16 + fc * 4 + r;
        int nn = cbase + ni * 16 + fr;
        float v = acc[mi][ni][r];
        if (EPI == 0) {
          ((float*)C)[(size_t)mm * N + nn] = v + bias1[nn];
        } else {
          ((_Float16*)C)[(size_t)mm * N + nn] = (_Float16)(v + bias1[nn] + bias2[nn]);
        }
      }
    }
  }
}

// ---------------- persistent pipelined LSTM recurrence ----------------
// 256 wgs x 512 thr. wg w owns hidden units 4*wp..4*wp+3, wp=(w&7)*32+(w>>3).
// h exchange via MONOTONIC slot ring: writes (sc1, LLC) go to slot[tau+1] -
// a NEVER-REUSED address - so plain L2-CACHED reads of slot[tau] are fresh by
// construction (demand-fetch L2 cannot hold a copy predating the write).
// => no fences, no invalidation, L2 amortizes the h broadcast per XCD
// (LLC traffic ~1.5 MB/tick vs 49 MB with LLC-direct reads).
// Flag protocol = R5-proven strided+sleep. Regular launch; 1 wg/CU.
__global__ __launch_bounds__(512) void k_recur(const _Float16* __restrict__ Wp4,
                                               const _Float16* __restrict__ Wp0,
                                               const _Float16* __restrict__ X0bf,
                                               _Float16* __restrict__ hfrag0,
                                               _Float16* __restrict__ hfragH,
                                               _Float16* __restrict__ h2all,
                                               _Float16* __restrict__ concat,
                                               const float* __restrict__ bih,
                                               const float* __restrict__ bhh,
                                               const float* __restrict__ c0p,
                                               unsigned* __restrict__ sync) {
  extern __shared__ char lds[];
  _Float16* ldsW = (_Float16*)lds;                 // 65536 f16
  float* redbuf = (float*)(lds + 131072);          // [3][3][2][256]
  _Float16* hstage = (_Float16*)(lds + 131072);    // [3][128] (reused after redbuf)
  float* gbuf = (float*)(lds + 149504);            // [3][32][16]
  unsigned* arrive = sync + 64;                    // strided: arrive[w*32]

  const int w = blockIdx.x;
  const int wp = (w & 7) * 32 + (w >> 3);          // XCD-local unit-block remap
  const int tid = threadIdx.x, lane = tid & 63, wv = tid >> 6;
  const int tb = wv & 1, kq = wv >> 1;
  const int row = (lane >> 4) * 4, col = lane & 15;

  // preload LDS weights (linear copy; swizzle pre-applied by k_packw4)
  for (int i = 0; i < 16; ++i) {
    int eo = (i * 512 + tid) * 8;
    *(h16x8*)&ldsW[eo] = *(const h16x8*)(Wp4 + (size_t)w * 65536 + eo);
  }
  // Whh0 fragments in registers
  h16x8 w0reg[8];
#pragma unroll
  for (int i = 0; i < 8; ++i)
    w0reg[i] = *(const h16x8*)(Wp0 + (size_t)w * 16384 + ((size_t)(kq * 8 + i) * 64 + lane) * 8);

  // per-thread epilogue state (threads 0..127 own (b, ni))
  const int eb = tid >> 2, eni = tid & 3, en = wp * 4 + eni;
  float c0r = 0.f, c1r = 0.f, c2r = 0.f;
  float b1r[4] = {0, 0, 0, 0}, b2r[4] = {0, 0, 0, 0};
  if (tid < 128) {
    c0r = c0p[0 * BB * HH + eb * HH + en];
    c1r = c0p[1 * BB * HH + eb * HH + en];
    c2r = c0p[2 * BB * HH + eb * HH + en];
#pragma unroll
    for (int g = 0; g < 4; ++g) {
      b1r[g] = bih[1 * G4 + g * 1024 + en] + bhh[1 * G4 + g * 1024 + en];
      b2r[g] = bih[2 * G4 + g * 1024 + en] + bhh[2 * G4 + g * 1024 + en];
    }
  }
  // pack-phase constants: thread (pk_l, pk_r) stores layer pk_l, batch row pk_r
  const int pk_l = tid >> 5, pk_r = tid & 31;
  const size_t pk_idx = ((size_t)(((pk_r >> 4) * 32 + (wp >> 3)) * 64 + (pk_r & 15) +
                                  (((wp >> 1) & 3) << 4))) * 8 + 4 * (wp & 1);
  __syncthreads();

  for (int tau = 0; tau < 130; ++tau) {
    // read base: slot[tau]; write base: slot[tau+1] (monotonic, never reused)
    const _Float16* rb = (tau < 3) ? (hfrag0 + (size_t)tau * 98304)
                                   : (hfragH + (size_t)(tau - 3) * 98304);
    _Float16* wb = (tau + 1 < 3) ? (hfrag0 + (size_t)(tau + 1) * 98304)
                                 : (hfragH + (size_t)(tau - 2) * 98304);
    const _Float16* h0r = rb;
    const _Float16* h1r = rb + 32768;
    const _Float16* h2r = rb + 65536;

    // A fragments: plain cached loads (L2-amortized per XCD; freshness by
    // construction - addresses are written exactly once, before the flag)
    h16x8 a0[8], a1[8], a2[8];
#pragma unroll
    for (int i = 0; i < 8; ++i) {
      int ks = kq * 8 + i;
      size_t off = ((size_t)(tb * 32 + ks) * 64 + lane) * 8;
      a0[i] = *(const h16x8*)(h0r + off);
      a1[i] = *(const h16x8*)(h1r + off);
      a2[i] = *(const h16x8*)(h2r + off);
    }
    // X0 gate loads: cached (L2 warm - no invalidation anywhere)
    float xg0 = 0.f, xg1 = 0.f, xg2 = 0.f, xg3 = 0.f;
    if (tid < 128 && tau < 128) {
      size_t xb = ((size_t)(tau * BB + eb)) * G4 + en;
      xg0 = (float)X0bf[xb];        xg1 = (float)X0bf[xb + 1024];
      xg2 = (float)X0bf[xb + 2048]; xg3 = (float)X0bf[xb + 3072];
    }
    f32x4 acc0 = {}, acc1 = {}, acc2 = {};
#pragma unroll
    for (int i = 0; i < 8; ++i) {
      int ks = kq * 8 + i;
      int jj = lane & 15, q = lane >> 4;
      int kk = (ks * 32 + q * 8) ^ ((jj & 7) << 3);
      const h16x8 bw1i = *(const h16x8*)&ldsW[0 * 16384 + jj * 1024 + kk];
      const h16x8 bw1h = *(const h16x8*)&ldsW[1 * 16384 + jj * 1024 + kk];
      const h16x8 bw2i = *(const h16x8*)&ldsW[2 * 16384 + jj * 1024 + kk];
      const h16x8 bw2h = *(const h16x8*)&ldsW[3 * 16384 + jj * 1024 + kk];
      acc0 = __builtin_amdgcn_mfma_f32_16x16x32_f16(a0[i], w0reg[i], acc0, 0, 0, 0);
      acc1 = __builtin_amdgcn_mfma_f32_16x16x32_f16(a0[i], bw1i, acc1, 0, 0, 0);
      acc1 = __builtin_amdgcn_mfma_f32_16x16x32_f16(a1[i], bw1h, acc1, 0, 0, 0);
      acc2 = __builtin_amdgcn_mfma_f32_16x16x32_f16(a1[i], bw2i, acc2, 0, 0, 0);
      acc2 = __builtin_amdgcn_mfma_f32_16x16x32_f16(a2[i], bw2h, acc2, 0, 0, 0);
    }
    // cross-wave K reduction
    if (kq >= 1) {
      int s = kq - 1;
#pragma unroll
      for (int r = 0; r < 4; ++r) {
        redbuf[((0 * 3 + s) * 2 + tb) * 256 + (row + r) * 16 + col] = acc0[r];
        redbuf[((1 * 3 + s) * 2 + tb) * 256 + (row + r) * 16 + col] = acc1[r];
        redbuf[((2 * 3 + s) * 2 + tb) * 256 + (row + r) * 16 + col] = acc2[r];
      }
    }
    __syncthreads();
    if (kq == 0) {
#pragma unroll
      for (int r = 0; r < 4; ++r) {
        float v0 = acc0[r], v1 = acc1[r], v2 = acc2[r];
#pragma unroll
        for (int s = 0; s < 3; ++s) {
          v0 += redbuf[((0 * 3 + s) * 2 + tb) * 256 + (row + r) * 16 + col];
          v1 += redbuf[((1 * 3 + s) * 2 + tb) * 256 + (row + r) * 16 + col];
          v2 += redbuf[((2 * 3 + s) * 2 + tb) * 256 + (row + r) * 16 + col];
        }
        gbuf[(0 * 32 + tb * 16 + row + r) * 16 + col] = v0;
        gbuf[(1 * 32 + tb * 16 + row + r) * 16 + col] = v1;
        gbuf[(2 * 32 + tb * 16 + row + r) * 16 + col] = v2;
      }
    }
    __syncthreads();
    // elementwise LSTM epilogue -> hstage (LDS) + h2all/concat (regular stores)
    if (tid < 128) {
      if (tau < 128) {  // layer 0: X0 already holds x@Wih0^T + b_ih0 + b_hh0
        float gi = gbuf[(0 * 32 + eb) * 16 + eni] + xg0;
        float gf = gbuf[(0 * 32 + eb) * 16 + 4 + eni] + xg1;
        float gg = gbuf[(0 * 32 + eb) * 16 + 8 + eni] + xg2;
        float go = gbuf[(0 * 32 + eb) * 16 + 12 + eni] + xg3;
        c0r = sigmf(gf) * c0r + sigmf(gi) * tanhf(gg);
        hstage[0 * 128 + tid] = (_Float16)(sigmf(go) * tanhf(c0r));
      }
      if (tau >= 1 && tau < 129) {  // layer 1
        float gi = gbuf[(1 * 32 + eb) * 16 + eni] + b1r[0];
        float gf = gbuf[(1 * 32 + eb) * 16 + 4 + eni] + b1r[1];
        float gg = gbuf[(1 * 32 + eb) * 16 + 8 + eni] + b1r[2];
        float go = gbuf[(1 * 32 + eb) * 16 + 12 + eni] + b1r[3];
        c1r = sigmf(gf) * c1r + sigmf(gi) * tanhf(gg);
        hstage[1 * 128 + tid] = (_Float16)(sigmf(go) * tanhf(c1r));
      }
      if (tau >= 2) {  // layer 2
        float gi = gbuf[(2 * 32 + eb) * 16 + eni] + b2r[0];
        float gf = gbuf[(2 * 32 + eb) * 16 + 4 + eni] + b2r[1];
        float gg = gbuf[(2 * 32 + eb) * 16 + 8 + eni] + b2r[2];
        float go = gbuf[(2 * 32 + eb) * 16 + 12 + eni] + b2r[3];
        c2r = sigmf(gf) * c2r + sigmf(gi) * tanhf(gg);
        float h = sigmf(go) * tanhf(c2r);
        _Float16 hb = (_Float16)h;
        hstage[2 * 128 + tid] = hb;
        int t2 = tau - 2;
        h2all[(size_t)(t2 * BB + eb) * HH + en] = hb;
        concat[(size_t)(t2 * BB + eb) * 2048 + 1024 + en] = hb;
      }
    }
    __syncthreads();   // hstage visible in LDS
    // pack phase: 96 threads emit one 8B agent-scope (sc1) store to slot[tau+1]
    {
      bool act = (tid < 96) &&
                 ((pk_l == 0) ? (tau < 128)
                  : (pk_l == 1) ? (tau >= 1 && tau < 129)
                                : (tau >= 2 && tau < 129));
      if (act) {
        unsigned long long v = *(const unsigned long long*)&hstage[pk_l * 128 + pk_r * 4];
        __hip_atomic_store(
            (unsigned long long*)(wb + (size_t)pk_l * 32768 + pk_idx), v,
            __ATOMIC_RELAXED, __HIP_MEMORY_SCOPE_AGENT);
      }
      asm volatile("s_waitcnt vmcnt(0)" ::: "memory");   // own sc1 stores at LLC
    }
    __syncthreads();   // all pack stores complete before flag
    if (tid == 0)
      __hip_atomic_store(&arrive[w * 32], (unsigned)(tau + 1), __ATOMIC_RELAXED,
                         __HIP_MEMORY_SCOPE_AGENT);
    if (tau < 129) {   // last tick: no one consumes, skip the wait
      if (tid < 64) {
        for (;;) {
          bool ok = true;
#pragma unroll
          for (int j = 0; j < 4; ++j) {
            unsigned v = __hip_atomic_load(&arrive[(tid * 4 + j) * 32], __ATOMIC_RELAXED,
                                           __HIP_MEMORY_SCOPE_AGENT);
            ok &= (v >= (unsigned)(tau + 1));
          }
          if (__all(ok)) break;
          __builtin_amdgcn_s_sleep(1);
        }
        // no cache maintenance needed: next tick's reads hit never-before-
        // accessed addresses (monotonic ring) -> demand-fetch is fresh
        asm volatile("" ::: "memory");
      }
      __syncthreads();
    }
  }
}

// ---------------- fused scores+softmax+weighted-context per (t,b) ----------------
__global__ __launch_bounds__(256) void k_attn(const _Float16* __restrict__ target,
                                              const _Float16* __restrict__ encb,
                                              _Float16* __restrict__ concat) {
  __shared__ float sc[64];
  __shared__ float att[64];
  int m = blockIdx.x, b = m & 31;
  int tid = threadIdx.x, lane = tid & 63, wv = tid >> 6;
  const h16x8* tp = (const h16x8*)(target + (size_t)m * EE + lane * 16);
  h16x8 tg0 = tp[0], tg1 = tp[1];
  for (int si = 0; si < 16; ++si) {
    int s = wv * 16 + si;
    const h16x8* ep = (const h16x8*)(encb + ((size_t)s * BB + b) * EE + lane * 16);
    h16x8 e0 = ep[0], e1 = ep[1];
    float a = 0.f;
#pragma unroll
    for (int j = 0; j < 8; ++j) a += (float)e0[j] * (float)tg0[j];
#pragma unroll
    for (int j = 0; j < 8; ++j) a += (float)e1[j] * (float)tg1[j];
#pragma unroll
    for (int off = 32; off >= 1; off >>= 1) a += __shfl_xor(a, off);
    if (lane == 0) sc[s] = a;
  }
  __syncthreads();
  if (wv == 0) {
    float v = sc[lane], mx = v;
#pragma unroll
    for (int off = 32; off >= 1; off >>= 1) mx = fmaxf(mx, __shfl_xor(mx, off));
    float e = expf(v - mx), sm = e;
#pragma unroll
    for (int off = 32; off >= 1; off >>= 1) sm += __shfl_xor(sm, off);
    att[lane] = e / sm;
  }
  __syncthreads();
  int e4 = tid * 4;
  float a0 = 0, a1 = 0, a2 = 0, a3 = 0;
  for (int s = 0; s < 64; ++s) {
    float wgt = att[s];
    h16x4 ev = *(const h16x4*)(encb + ((size_t)s * BB + b) * EE + e4);
    a0 += wgt * (float)ev[0]; a1 += wgt * (float)ev[1];
    a2 += wgt * (float)ev[2]; a3 += wgt * (float)ev[3];
  }
  h16x4 o; o[0] = (_Float16)a0; o[1] = (_Float16)a1; o[2] = (_Float16)a2; o[3] = (_Float16)a3;
  *(h16x4*)(concat + (size_t)m * 2048 + e4) = o;
}

// ---------------- host ----------------
extern "C" void kernel_launch(void* const* d_in, const int* in_sizes, int n_in,
                              void* d_out, int out_size, void* d_ws, size_t ws_size,
                              hipStream_t stream) {
  const int* tokens = (const int*)d_in[0];
  const float* embW = (const float*)d_in[1];
  const float* Wih = (const float*)d_in[2];
  const float* Whh = (const float*)d_in[3];
  const float* bih = (const float*)d_in[4];
  const float* bhh = (const float*)d_in[5];
  const float* Win = (const float*)d_in[6];
  const float* Wout = (const float*)d_in[7];
  const float* finalb = (const float*)d_in[8];
  const float* enc = (const float*)d_in[9];
  const float* h0 = (const float*)d_in[10];
  const float* c0 = (const float*)d_in[11];
  (void)in_sizes; (void)n_in; (void)out_size;
  if (ws_size < WS_NEEDED) return;

  char* ws = (char*)d_ws;
  unsigned* sync = (unsigned*)(ws + OFF_SYNC);
  _Float16* hfrag0 = (_Float16*)(ws + OFF_HFRAG0);
  _Float16* hfragH = (_Float16*)(ws + OFF_HFRAGH);
  _Float16* emb = (_Float16*)(ws + OFF_EMB);
  _Float16* X0bf = (_Float16*)(ws + OFF_X0);
  _Float16* Wih0b = (_Float16*)(ws + OFF_WIH0);
  _Float16* Wp4 = (_Float16*)(ws + OFF_WP4);
  _Float16* Wp0 = (_Float16*)(ws + OFF_WP0);
  _Float16* embWb = (_Float16*)(ws + OFF_EMBW);
  _Float16* Winb = (_Float16*)(ws + OFF_WIN);
  _Float16* Woutb = (_Float16*)(ws + OFF_WOUT);
  _Float16* encb = (_Float16*)(ws + OFF_ENC);
  _Float16* h2all = (_Float16*)(ws + OFF_H2ALL);
  _Float16* concat = (_Float16*)(ws + OFF_CONCAT);
  _Float16* target = (_Float16*)(ws + OFF_TARGET);
  _Float16* ht = (_Float16*)(ws + OFF_HT);

  const unsigned LDSB = 155648;   // k_recur: 128KB weights + 18KB redbuf + 6KB gbuf
  const unsigned LDSG = 98304;    // k_gemm256: 3 slots x (A 16KB + B 16KB)
  static int lds_set = 0;
  if (!lds_set) {
    hipFuncSetAttribute((const void*)k_recur, hipFuncAttributeMaxDynamicSharedMemorySize,
                        (int)LDSB);
    hipFuncSetAttribute((const void*)k_gemm256<0>, hipFuncAttributeMaxDynamicSharedMemorySize,
                        (int)LDSG);
    hipFuncSetAttribute((const void*)k_gemm256<1>, hipFuncAttributeMaxDynamicSharedMemorySize,
                        (int)LDSG);
    lds_set = 1;   // attributes are sticky on the functions
  }

  // prep: converts / packs / init
  k_conv<<<4096, 256, 0, stream>>>(embW, embWb, VV * EE / 4);
  k_conv<<<1024, 256, 0, stream>>>(Wih, Wih0b, G4 * EE / 4);       // layer-0 W_ih
  k_conv<<<512, 256, 0, stream>>>(Win, Winb, EE * EE / 4);
  k_conv<<<512, 256, 0, stream>>>(Wout, Woutb, EE * 2048 / 4);
  k_conv<<<512, 256, 0, stream>>>(enc, encb, 64 * BB * EE / 4);
  k_gather<<<NROWS, 256, 0, stream>>>(tokens, embW, emb);
  k_packw4<<<8192, 256, 0, stream>>>(Wih, Whh, Wp4);
  k_packw0<<<4096, 256, 0, stream>>>(Whh, Wp0);
  k_init<<<384, 256, 0, stream>>>(h0, hfrag0, sync);

  // X0 = emb @ Wih0^T + b_ih0 + b_hh0   -> f16 [4096,4096]  (256-tile counted-vmcnt GEMM)
  k_gemm256<1><<<16 * 16, 512, LDSG, stream>>>(emb, Wih0b, X0bf, NROWS, G4, EE, bih, bhh);

  // recurrence: REGULAR launch (graph-capturable); co-residency structural
  k_recur<<<256, 512, LDSB, stream>>>(Wp4, Wp0, X0bf, hfrag0, hfragH, h2all, concat,
                                      bih, bhh, c0, sync);

  // attention chain
  k_gemm<1><<<32 * 8, 256, 0, stream>>>(h2all, Winb, target, NROWS, EE, EE, nullptr, nullptr);
  k_attn<<<NROWS, 256, 0, stream>>>(target, encb, concat);
  k_gemm<2><<<32 * 8, 256, 0, stream>>>(concat, Woutb, ht, NROWS, EE, 2048, nullptr, nullptr);

  // logits = ht @ embW^T + final_b  -> f32 d_out  (256-tile counted-vmcnt GEMM)
  k_gemm256<0><<<16 * 125, 512, LDSG, stream>>>(ht, embWb, d_out, NROWS, VV, EE, finalb, nullptr);
}